// Round 10
// baseline (181.701 us; speedup 1.0000x reference)
//
#include <hip/hip_runtime.h>
#include <cstdint>
#include <cstddef>

// Problem constants
#define BSZ   2
#define QL    2048
#define DIMN  640
#define NH    8
#define CMAIN 512
#define AGGD  128
#define MROWS 4096                 // BSZ*QL
#define SCALE_QK 0.11180339887498948f   // (DIM/NHEADS)^-0.5 = 80^-0.5
#define C2EXP (SCALE_QK * 1.4426950408889634f)   // scale * log2(e)

typedef __bf16 bf16;
typedef __bf16 bf16x8 __attribute__((ext_vector_type(8)));
typedef __bf16 bf16x4v __attribute__((ext_vector_type(4)));
typedef float  f32x4  __attribute__((ext_vector_type(4)));

typedef __attribute__((address_space(1))) const uint32_t GU32;
typedef __attribute__((address_space(3))) uint32_t LU32;
#define GLL(g, l) __builtin_amdgcn_global_load_lds((GU32*)(g), (LU32*)(l), 16, 0, 0)

// hardware transcendentals (base-2): v_exp_f32 / v_log_f32
#define EXP2F(x) __builtin_amdgcn_exp2f(x)
#define LOG2F(x) __builtin_amdgcn_logf(x)

static __device__ __forceinline__ f32x4 mfma16(bf16x8 a, bf16x8 b, f32x4 c) {
    return __builtin_amdgcn_mfma_f32_16x16x32_bf16(a, b, c, 0, 0, 0);
}

static __device__ __forceinline__ void waitbar() {
    asm volatile("s_waitcnt vmcnt(0)" ::: "memory");
    __builtin_amdgcn_s_barrier();
    asm volatile("" ::: "memory");
}

// LDS tiles: rows of ROWB bytes, XOR-swizzled byte ^= (row&7)<<4.
// global_load_lds writes LDS linearly; swizzle applied by inverse-swizzling
// the per-lane GLOBAL source address (both-sides rule #21).
template<int ROWB>
static __device__ __forceinline__ bf16x8 ldsfragR(const bf16* base, int row, int kbyte) {
    return *(const bf16x8*)((const char*)base + row * ROWB + (kbyte ^ ((row & 7) << 4)));
}

// stage NCH 16B-chunks into LDS rows of ROWB bytes from global rows of strideB.
template<int NCH, int ROWB>
static __device__ __forceinline__ void stage_rowsR(bf16* ldsbuf, const char* gbase,
                                                   int strideB, int tid) {
    const int w = tid >> 6, lane = tid & 63;
    #pragma unroll
    for (int i = 0; i < NCH / 256; ++i) {
        int c = i * 256 + w * 64 + lane;
        int r = c / (ROWB / 16);
        int kb = ((c % (ROWB / 16)) * 16) ^ ((r & 7) << 4);   // inverse-swizzled
        GLL(gbase + (size_t)r * strideB + kb,
            (char*)ldsbuf + (size_t)(i * 256 + w * 64) * 16);
    }
}

// Plain-bf16 GEMM mainloop (fp32 MFMA accumulate). C = A*B; A [M][640] bf16,
// B^T [n][k=640] bf16. Block tile (MI*32)x128, 4 waves 2x2. Double-buffered.
template<int MI>
static __device__ __forceinline__ void gemm_main(
    const bf16* __restrict__ A, const bf16* __restrict__ BT,
    int m0, int n0, bf16* lds, f32x4 acc[MI][4])
{
    const int tid = threadIdx.x;
    const int w = tid >> 6, lane = tid & 63;
    const int lr = lane & 15, lg = lane >> 4;
    const int wm = (w >> 1) * (MI * 16), wn = (w & 1) * 64;
    constexpr int ASZ = MI * 2048;
    constexpr int BUF = ASZ + 8192;

    stage_rowsR<MI * 256, 128>(lds,   (const char*)(A + (size_t)m0 * 640), 1280, tid);
    stage_rowsR<1024, 128>(lds + ASZ, (const char*)(BT + (size_t)n0 * 640), 1280, tid);
    int cur = 0;
    #pragma unroll 1
    for (int ch = 0; ch < 10; ++ch) {
        waitbar();
        if (ch < 9) {
            int kk = (ch + 1) * 64;
            bf16* nb = lds + (cur ^ 1) * BUF;
            stage_rowsR<MI * 256, 128>(nb,   (const char*)(A + (size_t)m0 * 640 + kk), 1280, tid);
            stage_rowsR<1024, 128>(nb + ASZ, (const char*)(BT + (size_t)n0 * 640 + kk), 1280, tid);
        }
        const bf16* cA = lds + cur * BUF;
        const bf16* cB = cA + ASZ;
        #pragma unroll
        for (int ks = 0; ks < 2; ++ks) {
            bf16x8 a[MI], b[4];
            #pragma unroll
            for (int i = 0; i < MI; ++i) a[i] = ldsfragR<128>(cA, wm + i * 16 + lr, ks * 64 + lg * 16);
            #pragma unroll
            for (int i = 0; i < 4; ++i)  b[i] = ldsfragR<128>(cB, wn + i * 16 + lr, ks * 64 + lg * 16);
            #pragma unroll
            for (int mi = 0; mi < MI; ++mi)
                #pragma unroll
                for (int ni = 0; ni < 4; ++ni)
                    acc[mi][ni] = mfma16(a[mi], b[ni], acc[mi][ni]);
        }
        cur ^= 1;
    }
}

// ---- merged prep: blocks <2560: Q fp32->bf16; blocks >=2560: W transpose ----
__global__ void __launch_bounds__(256) k_prep(
    const float* __restrict__ Q, const float* __restrict__ WQ,
    const float* __restrict__ WK, const float* __restrict__ WV,
    const float* __restrict__ WO,
    bf16* __restrict__ Qbf, bf16* __restrict__ BTqkv, bf16* __restrict__ BTout)
{
    __shared__ float tl[64][65];
    const int tid = threadIdx.x;
    if (blockIdx.x < 2560) {
        int i = blockIdx.x * 256 + tid;
        float4 v = ((const float4*)Q)[i];
        bf16x4v hv;
        hv[0] = (bf16)v.x; hv[1] = (bf16)v.y; hv[2] = (bf16)v.z; hv[3] = (bf16)v.w;
        *(bf16x4v*)(Qbf + (size_t)i * 4) = hv;
        return;
    }
    const int f = blockIdx.x - 2560;          // 0..399
    const int wsel = f / 100;
    const int rem = f - wsel * 100;
    const int ty = rem / 10, tx = rem - (rem / 10) * 10;
    const float* W = (wsel == 0) ? WQ : (wsel == 1) ? WK : (wsel == 2) ? WV : WO;
    const int rr = tid >> 4;
    const int cc = (tid & 15) * 4;
    #pragma unroll
    for (int i = 0; i < 4; ++i) {
        int k = tx * 64 + rr + i * 16;
        float4 v = *(const float4*)(W + (size_t)k * 640 + ty * 64 + cc);
        tl[cc + 0][rr + i * 16] = v.x;
        tl[cc + 1][rr + i * 16] = v.y;
        tl[cc + 2][rr + i * 16] = v.z;
        tl[cc + 3][rr + i * 16] = v.w;
    }
    __syncthreads();
    bf16* dst; int nbase;
    if (wsel < 3) { dst = BTqkv; nbase = wsel * 640 + ty * 64; }
    else          { dst = BTout; nbase = ty * 64; }
    const int nl0 = tid >> 4;
    const int kl = (tid & 15) * 4;
    #pragma unroll
    for (int i = 0; i < 4; ++i) {
        int nl = nl0 + i * 16;
        bf16x4v hv;
        #pragma unroll
        for (int j = 0; j < 4; ++j) hv[j] = (bf16)tl[nl][kl + j];
        *(bf16x4v*)(dst + (size_t)(nbase + nl) * 640 + tx * 64 + kl) = hv;
    }
}

// ---- QKV GEMM: C[4096][1920] ; epilogue adds bias (+W_pos) and routes outputs
__global__ void __launch_bounds__(256) k_gemm_qkv(
    const bf16* __restrict__ Qbf, const bf16* __restrict__ BT,
    const float* __restrict__ bQ, const float* __restrict__ bK, const float* __restrict__ bV,
    const float* __restrict__ Wpos,
    bf16* __restrict__ qsbuf, bf16* __restrict__ vsT, float* __restrict__ aggbuf)
{
    __shared__ __align__(16) bf16 lds[2 * (8192 + 8192)];   // 64 KB
    const int m0 = blockIdx.x * 128, n0 = blockIdx.y * 128;
    f32x4 acc[4][4];
    {
        f32x4 z = {0.f, 0.f, 0.f, 0.f};
        #pragma unroll
        for (int mi = 0; mi < 4; ++mi)
            #pragma unroll
            for (int ni = 0; ni < 4; ++ni) acc[mi][ni] = z;
    }
    gemm_main<4>(Qbf, BT, m0, n0, lds, acc);

    const int tid = threadIdx.x, w = tid >> 6, lane = tid & 63;
    const int lr = lane & 15, lg = lane >> 4;
    const int wm = (w >> 1) * 64, wn = (w & 1) * 64;
    const int p = n0 / 640;
    const float* bias = (p == 0) ? bQ : (p == 1) ? bK : bV;

    #pragma unroll
    for (int mi = 0; mi < 4; ++mi)
        #pragma unroll
        for (int ni = 0; ni < 4; ++ni) {
            int n = n0 + wn + ni * 16 + lr;
            int c = n - p * 640;
            int rbase = m0 + wm + mi * 16 + lg * 4;
            float bval = bias[c];
            if (c < 512) {
                int hh = c >> 6, d = c & 63;
                #pragma unroll
                for (int r = 0; r < 4; ++r) {
                    int rg = rbase + r;
                    int bb = rg >> 11, l = rg & 2047;
                    float v = acc[mi][ni][r] + bval + Wpos[(size_t)l * 512 + c];
                    if (p < 2)
                        qsbuf[(((size_t)(p * 2 + bb) * 8 + hh) * 2048 + l) * 64 + d] = (bf16)v;
                    else
                        vsT[(((size_t)(bb * 8 + hh)) * 64 + d) * 2048 + l] = (bf16)v;
                }
            } else {
                int j = c - 512;
                #pragma unroll
                for (int r = 0; r < 4; ++r) {
                    int rg = rbase + r;
                    aggbuf[((size_t)p * MROWS + rg) * AGGD + j] = acc[mi][ni][r] + bval;
                }
            }
        }
}

// ---- attention (R7 internals) + fused agg tail for h==0 blocks.
// 4-wave blocks, 64 q-rows, grid (32,16), LDS 80 KB (2 blocks/CU).
// NO-MAX softmax, swapped QK^T (lane-local P rows).
// pass1: BK=128 (16 tiles); pass2: BK=128 (16 tiles), counted vmcnt(8).
__global__ void __launch_bounds__(256) k_attn(const bf16* __restrict__ qsbuf, const bf16* __restrict__ vsT,
                                              float* __restrict__ gattn, bf16* __restrict__ xcat,
                                              const float* __restrict__ aggbuf,
                                              const float* __restrict__ Wagg,
                                              const float* __restrict__ bagg)
{
    __shared__ __align__(16) bf16 smem[2][16384];       // 64 KB: K[128][128B] + V[64][256B]
    __shared__ __align__(16) bf16 p_lds[4][16 * 128];   // 16 KB, per-wave [16 q][256B]

    const int bh = blockIdx.y;
    const int b = bh >> 3, h = bh & 7;
    const int q0 = blockIdx.x * 64;
    const int tid = threadIdx.x, w = tid >> 6, lane = tid & 63;
    const int lr = lane & 15, lg = lane >> 4;

    const bf16* qbase = qsbuf + (size_t)(b * 8 + h) * (2048 * 64);          // q
    const bf16* kbase = qsbuf + (size_t)((2 + b) * 8 + h) * (2048 * 64);    // k
    const bf16* vtb   = vsT + (size_t)(b * 8 + h) * (64 * 2048);

    bf16x8 aq[2];
    {
        const bf16* qp = qbase + (size_t)(q0 + w * 16 + lr) * 64 + lg * 8;
        aq[0] = *(const bf16x8*)(qp);
        aq[1] = *(const bf16x8*)(qp + 32);
    }

    // ---- pass 1: denominator sums, BK=128
    float lsum = 0.f;
    stage_rowsR<1024, 128>(smem[0], (const char*)kbase, 128, tid);
    int cur = 0;
    #pragma unroll 1
    for (int kt = 0; kt < 16; ++kt) {
        waitbar();
        if (kt < 15)
            stage_rowsR<1024, 128>(smem[cur ^ 1], (const char*)kbase + (size_t)(kt + 1) * 16384, 128, tid);
        __builtin_amdgcn_sched_barrier(0);
        const bf16* kb = smem[cur];
        f32x4 s[8];
        {
            f32x4 z = {0.f, 0.f, 0.f, 0.f};
            #pragma unroll
            for (int ni = 0; ni < 8; ++ni) s[ni] = z;
        }
        #pragma unroll
        for (int ks = 0; ks < 2; ++ks)
            #pragma unroll
            for (int ni = 0; ni < 8; ++ni)
                s[ni] = mfma16(ldsfragR<128>(kb, ni * 16 + lr, ks * 64 + lg * 16), aq[ks], s[ni]);
        #pragma unroll
        for (int ni = 0; ni < 8; ++ni)
            #pragma unroll
            for (int r = 0; r < 4; ++r)
                lsum += EXP2F(s[ni][r] * C2EXP);
        cur ^= 1;
    }
    lsum += __shfl_xor(lsum, 16);
    lsum += __shfl_xor(lsum, 32);
    const float l2i = -LOG2F(lsum);

    f32x4 o[4];
    {
        f32x4 z = {0.f, 0.f, 0.f, 0.f};
        #pragma unroll
        for (int ni = 0; ni < 4; ++ni) o[ni] = z;
    }
    float* attnrow = gattn + (size_t)bh * 2048 * 2048 + (size_t)(q0 + w * 16 + lr) * 2048;

    // ---- pass 2: BK=128; K in smem[cur][0..8191], V^T in smem[cur][8192..]
    stage_rowsR<1024, 128>(smem[0],        (const char*)kbase, 128, tid);
    stage_rowsR<1024, 256>(smem[0] + 8192, (const char*)vtb, 4096, tid);
    cur = 0;
    #pragma unroll 1
    for (int kt = 0; kt < 16; ++kt) {
        // drain the 8 staging loads; stores (8/lane, newer in FIFO) may remain
        if (kt == 0) asm volatile("s_waitcnt vmcnt(0)" ::: "memory");
        else         asm volatile("s_waitcnt vmcnt(8)" ::: "memory");
        __builtin_amdgcn_s_barrier();
        asm volatile("" ::: "memory");
        if (kt < 15) {
            stage_rowsR<1024, 128>(smem[cur ^ 1],        (const char*)kbase + (size_t)(kt + 1) * 16384, 128, tid);
            stage_rowsR<1024, 256>(smem[cur ^ 1] + 8192, (const char*)vtb + (size_t)(kt + 1) * 256, 4096, tid);
        }
        __builtin_amdgcn_sched_barrier(0);   // keep staging issue ahead of compute/stores
        const bf16* kb = smem[cur];
        const bf16* vb = smem[cur] + 8192;
        f32x4 s[8];
        {
            f32x4 z = {0.f, 0.f, 0.f, 0.f};
            #pragma unroll
            for (int ni = 0; ni < 8; ++ni) s[ni] = z;
        }
        #pragma unroll
        for (int ks = 0; ks < 2; ++ks)
            #pragma unroll
            for (int ni = 0; ni < 8; ++ni)
                s[ni] = mfma16(ldsfragR<128>(kb, ni * 16 + lr, ks * 64 + lg * 16), aq[ks], s[ni]);
        bf16* pl = &p_lds[w][0];
        float* arow = attnrow + kt * 128;
        #pragma unroll
        for (int ni = 0; ni < 8; ++ni) {
            f32x4 p;
            #pragma unroll
            for (int r = 0; r < 4; ++r) p[r] = EXP2F(fmaf(s[ni][r], C2EXP, l2i));
            *(f32x4*)(arow + ni * 16 + lg * 4) = p;          // dwordx4 attn store
            bf16x4v pb;
            #pragma unroll
            for (int r = 0; r < 4; ++r) pb[r] = (bf16)p[r];
            *(bf16x4v*)((char*)pl + lr * 256 + ((ni * 32 + lg * 8) ^ ((lr & 7) << 4))) = pb;
        }
        #pragma unroll
        for (int ks = 0; ks < 4; ++ks) {
            bf16x8 pa = ldsfragR<256>(pl, lr, ks * 64 + lg * 16);
            #pragma unroll
            for (int ni = 0; ni < 4; ++ni)
                o[ni] = mfma16(pa, ldsfragR<256>(vb, ni * 16 + lr, ks * 64 + lg * 16), o[ni]);
        }
        cur ^= 1;
    }

    #pragma unroll
    for (int ni = 0; ni < 4; ++ni) {
        #pragma unroll
        for (int r = 0; r < 4; ++r) {
            int qr = q0 + w * 16 + lg * 4 + r;
            size_t rg = (size_t)b * 2048 + qr;
            int c = h * 64 + ni * 16 + lr;
            xcat[rg * 640 + c] = (bf16)o[ni][r];
        }
    }

    // ---- fused agg tail (h==0 blocks only): xcat cols 512..639 for 64 rows.
    if (h == 0) {
        __syncthreads();                       // main loop done with smem/p_lds
        float* wl = (float*)&smem[0][0];       // 64 KB: Wagg[128][128]
        float* xl = (float*)&p_lds[0][0];      // 16 KB: xl[32][128]
        for (int i = tid; i < 128 * 128; i += 256) wl[i] = Wagg[i];
        #pragma unroll
        for (int half = 0; half < 2; ++half) {
            size_t r0 = (size_t)b * 2048 + q0 + half * 32;
            __syncthreads();
            for (int i = tid; i < 32 * 128; i += 256) {
                int row = i >> 7, j = i & 127;
                size_t rg = r0 + row;
                float s = aggbuf[rg * AGGD + j]
                        + aggbuf[((size_t)MROWS + rg) * AGGD + j]
                        + aggbuf[((size_t)2 * MROWS + rg) * AGGD + j];
                xl[i] = s * (1.0f / 3.0f);
            }
            __syncthreads();
            const int row = tid >> 3;
            const int jo0 = (tid & 7) * 16;
            float acc[16];
            #pragma unroll
            for (int jj = 0; jj < 16; ++jj) acc[jj] = 0.f;
            for (int j = 0; j < 128; ++j) {
                float xv = xl[row * 128 + j];
                const float* wr = &wl[j * 128 + jo0];
                #pragma unroll
                for (int jj = 0; jj < 16; ++jj) acc[jj] = fmaf(xv, wr[jj], acc[jj]);
            }
            size_t rg = r0 + row;
            #pragma unroll
            for (int jj = 0; jj < 16; ++jj) {
                float t = acc[jj] + bagg[jo0 + jj];
                float g = 0.5f * t * (1.0f + tanhf(0.7978845608028654f * (t + 0.044715f * t * t * t)));
                xcat[rg * 640 + 512 + jo0 + jj] = (bf16)g;
            }
        }
    }
}

// ---- out GEMM (BM=64: 320 blocks): d_out = xcat @ W_out + b_out
__global__ void __launch_bounds__(256) k_gemm_out(
    const bf16* __restrict__ X, const bf16* __restrict__ BT,
    const float* __restrict__ bout, float* __restrict__ out0)
{
    __shared__ __align__(16) bf16 lds[2 * (4096 + 8192)];   // 48 KB
    const int m0 = blockIdx.x * 64, n0 = blockIdx.y * 128;
    f32x4 acc[2][4];
    {
        f32x4 z = {0.f, 0.f, 0.f, 0.f};
        #pragma unroll
        for (int mi = 0; mi < 2; ++mi)
            #pragma unroll
            for (int ni = 0; ni < 4; ++ni) acc[mi][ni] = z;
    }
    gemm_main<2>(X, BT, m0, n0, lds, acc);

    const int tid = threadIdx.x, w = tid >> 6, lane = tid & 63;
    const int lr = lane & 15, lg = lane >> 4;
    const int wm = (w >> 1) * 32, wn = (w & 1) * 64;
    #pragma unroll
    for (int mi = 0; mi < 2; ++mi)
        #pragma unroll
        for (int ni = 0; ni < 4; ++ni) {
            int n = n0 + wn + ni * 16 + lr;
            float bv = bout[n];
            #pragma unroll
            for (int r = 0; r < 4; ++r) {
                int rg = m0 + wm + mi * 16 + lg * 4 + r;
                out0[(size_t)rg * 640 + n] = acc[mi][ni][r] + bv;
            }
        }
}

extern "C" void kernel_launch(void* const* d_in, const int* in_sizes, int n_in,
                              void* d_out, int out_size, void* d_ws, size_t ws_size,
                              hipStream_t stream)
{
    (void)in_sizes; (void)n_in; (void)out_size; (void)ws_size;
    const float* Q    = (const float*)d_in[0];
    const float* WQ   = (const float*)d_in[1];
    const float* bQ   = (const float*)d_in[2];
    const float* WK   = (const float*)d_in[3];
    const float* bK   = (const float*)d_in[4];
    const float* WV   = (const float*)d_in[5];
    const float* bV   = (const float*)d_in[6];
    const float* Wpos = (const float*)d_in[7];
    const float* Wagg = (const float*)d_in[8];
    const float* bagg = (const float*)d_in[9];
    const float* WO   = (const float*)d_in[10];
    const float* bout = (const float*)d_in[11];

    float* out0  = (float*)d_out;
    float* gattn = out0 + (size_t)MROWS * DIMN;   // attn output region (268 MB)

    char* ws = (char*)d_ws;
    bf16* Qbf    = (bf16*)(ws);                 ws += (size_t)MROWS * DIMN * 2;      // 5.24 MB
    bf16* BTqkv  = (bf16*)(ws);                 ws += (size_t)1920 * 640 * 2;        // 2.46 MB
    bf16* BTout  = (bf16*)(ws);                 ws += (size_t)640 * 640 * 2;         // 0.82 MB
    bf16* qsbuf  = (bf16*)(ws);                 ws += (size_t)4 * 8 * 2048 * 64 * 2; // 8 MB (q+k)
    bf16* vsT    = (bf16*)(ws);                 ws += (size_t)16 * 64 * 2048 * 2;    // 4 MB
    float* aggbuf= (float*)(ws);                ws += (size_t)3 * MROWS * AGGD * 4;  // 6 MB
    bf16* xcat   = (bf16*)(ws);                 ws += (size_t)MROWS * DIMN * 2;      // 5.24 MB

    k_prep<<<dim3(2960), dim3(256), 0, stream>>>(Q, WQ, WK, WV, WO, Qbf, BTqkv, BTout);
    k_gemm_qkv<<<dim3(32, 15), dim3(256), 0, stream>>>(Qbf, BTqkv,
                                                       bQ, bK, bV, Wpos, qsbuf, vsT, aggbuf);
    k_attn<<<dim3(32, 16), dim3(256), 0, stream>>>(qsbuf, vsT, gattn, xcat,
                                                   aggbuf, Wagg, bagg);
    k_gemm_out<<<dim3(64, 5), dim3(256), 0, stream>>>(xcat, BTout, bout, out0);
}

// Round 11
// 174.295 us; speedup vs baseline: 1.0425x; 1.0425x over previous
//
#include <hip/hip_runtime.h>
#include <cstdint>
#include <cstddef>

// Problem constants
#define BSZ   2
#define QL    2048
#define DIMN  640
#define NH    8
#define CMAIN 512
#define AGGD  128
#define MROWS 4096                 // BSZ*QL
#define SCALE_QK 0.11180339887498948f   // (DIM/NHEADS)^-0.5 = 80^-0.5
#define C2EXP (SCALE_QK * 1.4426950408889634f)   // scale * log2(e)

typedef __bf16 bf16;
typedef __bf16 bf16x8 __attribute__((ext_vector_type(8)));
typedef __bf16 bf16x4v __attribute__((ext_vector_type(4)));
typedef float  f32x4  __attribute__((ext_vector_type(4)));

typedef __attribute__((address_space(1))) const uint32_t GU32;
typedef __attribute__((address_space(3))) uint32_t LU32;
#define GLL(g, l) __builtin_amdgcn_global_load_lds((GU32*)(g), (LU32*)(l), 16, 0, 0)

// hardware transcendentals (base-2): v_exp_f32 / v_log_f32
#define EXP2F(x) __builtin_amdgcn_exp2f(x)
#define LOG2F(x) __builtin_amdgcn_logf(x)

static __device__ __forceinline__ f32x4 mfma16(bf16x8 a, bf16x8 b, f32x4 c) {
    return __builtin_amdgcn_mfma_f32_16x16x32_bf16(a, b, c, 0, 0, 0);
}

static __device__ __forceinline__ void waitbar() {
    asm volatile("s_waitcnt vmcnt(0)" ::: "memory");
    __builtin_amdgcn_s_barrier();
    asm volatile("" ::: "memory");
}

// LDS tiles: rows of ROWB bytes, XOR-swizzled byte ^= (row&7)<<4.
// global_load_lds writes LDS linearly, so the swizzle is applied by
// inverse-swizzling the per-lane GLOBAL source address (both-sides rule #21).
template<int ROWB>
static __device__ __forceinline__ bf16x8 ldsfragR(const bf16* base, int row, int kbyte) {
    return *(const bf16x8*)((const char*)base + row * ROWB + (kbyte ^ ((row & 7) << 4)));
}

// stage NCH 16B-chunks into LDS rows of ROWB bytes from global rows of strideB.
template<int NCH, int ROWB>
static __device__ __forceinline__ void stage_rowsR(bf16* ldsbuf, const char* gbase,
                                                   int strideB, int tid) {
    const int w = tid >> 6, lane = tid & 63;
    #pragma unroll
    for (int i = 0; i < NCH / 256; ++i) {
        int c = i * 256 + w * 64 + lane;
        int r = c / (ROWB / 16);
        int kb = ((c % (ROWB / 16)) * 16) ^ ((r & 7) << 4);   // inverse-swizzled
        GLL(gbase + (size_t)r * strideB + kb,
            (char*)ldsbuf + (size_t)(i * 256 + w * 64) * 16);
    }
}

// Plain-bf16 GEMM mainloop (fp32 MFMA accumulate). C = A*B; A [M][640] bf16,
// B^T [n][k=640] bf16. Block tile (MI*32)x128, 4 waves 2x2. Double-buffered,
// 1 barrier per 64-K chunk, 10 chunks.
template<int MI>
static __device__ __forceinline__ void gemm_main(
    const bf16* __restrict__ A, const bf16* __restrict__ BT,
    int m0, int n0, bf16* lds, f32x4 acc[MI][4])
{
    const int tid = threadIdx.x;
    const int w = tid >> 6, lane = tid & 63;
    const int lr = lane & 15, lg = lane >> 4;
    const int wm = (w >> 1) * (MI * 16), wn = (w & 1) * 64;
    constexpr int ASZ = MI * 2048;          // A-tile bf16 elems (MI*32 rows x 64)
    constexpr int BUF = ASZ + 8192;

    stage_rowsR<MI * 256, 128>(lds,   (const char*)(A + (size_t)m0 * 640), 1280, tid);
    stage_rowsR<1024, 128>(lds + ASZ, (const char*)(BT + (size_t)n0 * 640), 1280, tid);
    int cur = 0;
    #pragma unroll 1
    for (int ch = 0; ch < 10; ++ch) {
        waitbar();
        if (ch < 9) {
            int kk = (ch + 1) * 64;
            bf16* nb = lds + (cur ^ 1) * BUF;
            stage_rowsR<MI * 256, 128>(nb,   (const char*)(A + (size_t)m0 * 640 + kk), 1280, tid);
            stage_rowsR<1024, 128>(nb + ASZ, (const char*)(BT + (size_t)n0 * 640 + kk), 1280, tid);
        }
        const bf16* cA = lds + cur * BUF;
        const bf16* cB = cA + ASZ;
        #pragma unroll
        for (int ks = 0; ks < 2; ++ks) {
            bf16x8 a[MI], b[4];
            #pragma unroll
            for (int i = 0; i < MI; ++i) a[i] = ldsfragR<128>(cA, wm + i * 16 + lr, ks * 64 + lg * 16);
            #pragma unroll
            for (int i = 0; i < 4; ++i)  b[i] = ldsfragR<128>(cB, wn + i * 16 + lr, ks * 64 + lg * 16);
            #pragma unroll
            for (int mi = 0; mi < MI; ++mi)
                #pragma unroll
                for (int ni = 0; ni < 4; ++ni)
                    acc[mi][ni] = mfma16(a[mi], b[ni], acc[mi][ni]);
        }
        cur ^= 1;
    }
}

// ---- prep: Q (4096x640 f32) -> bf16 ----
__global__ void __launch_bounds__(256) k_split_q(const float* __restrict__ Q,
                                                 bf16* __restrict__ Qbf) {
    int i = blockIdx.x * 256 + threadIdx.x;
    float4 v = ((const float4*)Q)[i];
    bf16x4v hv;
    hv[0] = (bf16)v.x; hv[1] = (bf16)v.y; hv[2] = (bf16)v.z; hv[3] = (bf16)v.w;
    *(bf16x4v*)(Qbf + (size_t)i * 4) = hv;
}

// ---- prep: coalesced LDS-transpose of W_Q/W_K/W_V/W_out into B^T bf16.
__global__ void __launch_bounds__(256) k_prep_w(
    const float* __restrict__ WQ, const float* __restrict__ WK,
    const float* __restrict__ WV, const float* __restrict__ WO,
    bf16* __restrict__ BTqkv, bf16* __restrict__ BTout)
{
    __shared__ float tl[64][65];     // tl[n_loc][k_loc]
    const int ty = blockIdx.x / 10, tx = blockIdx.x % 10;
    const int wsel = blockIdx.y;
    const float* W = (wsel == 0) ? WQ : (wsel == 1) ? WK : (wsel == 2) ? WV : WO;
    const int tid = threadIdx.x;
    const int rr = tid >> 4;             // k row group 0..15
    const int cc = (tid & 15) * 4;       // n col 0..60
    #pragma unroll
    for (int i = 0; i < 4; ++i) {
        int k = tx * 64 + rr + i * 16;
        float4 v = *(const float4*)(W + (size_t)k * 640 + ty * 64 + cc);
        tl[cc + 0][rr + i * 16] = v.x;
        tl[cc + 1][rr + i * 16] = v.y;
        tl[cc + 2][rr + i * 16] = v.z;
        tl[cc + 3][rr + i * 16] = v.w;
    }
    __syncthreads();
    bf16* dst; int nbase;
    if (wsel < 3) { dst = BTqkv; nbase = wsel * 640 + ty * 64; }
    else          { dst = BTout; nbase = ty * 64; }
    const int nl0 = tid >> 4;
    const int kl = (tid & 15) * 4;
    #pragma unroll
    for (int i = 0; i < 4; ++i) {
        int nl = nl0 + i * 16;
        bf16x4v hv;
        #pragma unroll
        for (int j = 0; j < 4; ++j) hv[j] = (bf16)tl[nl][kl + j];
        *(bf16x4v*)(dst + (size_t)(nbase + nl) * 640 + tx * 64 + kl) = hv;
    }
}

// ---- QKV GEMM: C[4096][1920] ; epilogue adds bias (+W_pos) and routes outputs
__global__ void __launch_bounds__(256) k_gemm_qkv(
    const bf16* __restrict__ Qbf, const bf16* __restrict__ BT,
    const float* __restrict__ bQ, const float* __restrict__ bK, const float* __restrict__ bV,
    const float* __restrict__ Wpos,
    bf16* __restrict__ qsbuf, bf16* __restrict__ vsT, float* __restrict__ aggbuf)
{
    __shared__ __align__(16) bf16 lds[2 * (8192 + 8192)];   // 64 KB
    const int m0 = blockIdx.x * 128, n0 = blockIdx.y * 128;
    f32x4 acc[4][4];
    {
        f32x4 z = {0.f, 0.f, 0.f, 0.f};
        #pragma unroll
        for (int mi = 0; mi < 4; ++mi)
            #pragma unroll
            for (int ni = 0; ni < 4; ++ni) acc[mi][ni] = z;
    }
    gemm_main<4>(Qbf, BT, m0, n0, lds, acc);

    const int tid = threadIdx.x, w = tid >> 6, lane = tid & 63;
    const int lr = lane & 15, lg = lane >> 4;
    const int wm = (w >> 1) * 64, wn = (w & 1) * 64;
    const int p = n0 / 640;                       // block-uniform (640 % 128 == 0)
    const float* bias = (p == 0) ? bQ : (p == 1) ? bK : bV;

    #pragma unroll
    for (int mi = 0; mi < 4; ++mi)
        #pragma unroll
        for (int ni = 0; ni < 4; ++ni) {
            int n = n0 + wn + ni * 16 + lr;
            int c = n - p * 640;
            int rbase = m0 + wm + mi * 16 + lg * 4;
            float bval = bias[c];
            if (c < 512) {
                int hh = c >> 6, d = c & 63;
                #pragma unroll
                for (int r = 0; r < 4; ++r) {
                    int rg = rbase + r;
                    int bb = rg >> 11, l = rg & 2047;
                    float v = acc[mi][ni][r] + bval + Wpos[(size_t)l * 512 + c];
                    if (p < 2)
                        qsbuf[(((size_t)(p * 2 + bb) * 8 + hh) * 2048 + l) * 64 + d] = (bf16)v;
                    else
                        vsT[(((size_t)(bb * 8 + hh)) * 64 + d) * 2048 + l] = (bf16)v;
                }
            } else {
                int j = c - 512;
                #pragma unroll
                for (int r = 0; r < 4; ++r) {
                    int rg = rbase + r;
                    aggbuf[((size_t)p * MROWS + rg) * AGGD + j] = acc[mi][ni][r] + bval;
                }
            }
        }
}

// ---- agg: x = mean3(aggbuf) ; gelu_tanh(x @ W_agg + b_agg) -> xcat cols 512..639
__global__ void __launch_bounds__(256) k_agg(const float* __restrict__ aggbuf,
                                             const float* __restrict__ Wagg, const float* __restrict__ bagg,
                                             bf16* __restrict__ xcat)
{
    __shared__ float wl[128 * 128];
    __shared__ float xl[32 * 128];
    const int tid = threadIdx.x;
    const int r0 = blockIdx.x * 32;
    for (int i = tid; i < 128 * 128; i += 256) wl[i] = Wagg[i];
    for (int i = tid; i < 32 * 128; i += 256) {
        int row = i >> 7, j = i & 127;
        size_t rg = r0 + row;
        float s = aggbuf[rg * AGGD + j]
                + aggbuf[((size_t)MROWS + rg) * AGGD + j]
                + aggbuf[((size_t)2 * MROWS + rg) * AGGD + j];
        xl[i] = s * (1.0f / 3.0f);
    }
    __syncthreads();
    const int row = tid >> 3;
    const int jo0 = (tid & 7) * 16;
    float acc[16];
    #pragma unroll
    for (int jj = 0; jj < 16; ++jj) acc[jj] = 0.f;
    for (int j = 0; j < 128; ++j) {
        float xv = xl[row * 128 + j];
        const float* wr = &wl[j * 128 + jo0];
        #pragma unroll
        for (int jj = 0; jj < 16; ++jj) acc[jj] = fmaf(xv, wr[jj], acc[jj]);
    }
    size_t rg = r0 + row;
    #pragma unroll
    for (int jj = 0; jj < 16; ++jj) {
        float t = acc[jj] + bagg[jo0 + jj];
        float g = 0.5f * t * (1.0f + tanhf(0.7978845608028654f * (t + 0.044715f * t * t * t)));
        xcat[rg * 640 + 512 + jo0 + jj] = (bf16)g;
    }
}

// ---- attention (R7 structure), NO-MAX softmax, swapped QK^T (lane-local P rows).
// pass1: BK=128; pass2: BK=128, counted vmcnt(8), NON-TEMPORAL attn stores
// (268 MB stream must not cycle L2/L3 and evict the K/V working set),
// s_setprio(1) around MFMA clusters (T5; independent blocks).
__global__ void __launch_bounds__(256) k_attn(const bf16* __restrict__ qsbuf, const bf16* __restrict__ vsT,
                                              float* __restrict__ gattn,
                                              bf16* __restrict__ xcat)
{
    __shared__ __align__(16) bf16 smem[2][16384];       // 64 KB: K[128][128B] + V[64][256B]
    __shared__ __align__(16) bf16 p_lds[4][16 * 128];   // 16 KB, per-wave [16 q][256B]

    const int bh = blockIdx.y;
    const int b = bh >> 3, h = bh & 7;
    const int q0 = blockIdx.x * 64;
    const int tid = threadIdx.x, w = tid >> 6, lane = tid & 63;
    const int lr = lane & 15, lg = lane >> 4;

    const bf16* qbase = qsbuf + (size_t)(b * 8 + h) * (2048 * 64);          // q
    const bf16* kbase = qsbuf + (size_t)((2 + b) * 8 + h) * (2048 * 64);    // k
    const bf16* vtb   = vsT + (size_t)(b * 8 + h) * (64 * 2048);

    bf16x8 aq[2];
    {
        const bf16* qp = qbase + (size_t)(q0 + w * 16 + lr) * 64 + lg * 8;
        aq[0] = *(const bf16x8*)(qp);
        aq[1] = *(const bf16x8*)(qp + 32);
    }

    // ---- pass 1: denominator sums, BK=128
    float lsum = 0.f;
    stage_rowsR<1024, 128>(smem[0], (const char*)kbase, 128, tid);
    int cur = 0;
    #pragma unroll 1
    for (int kt = 0; kt < 16; ++kt) {
        waitbar();
        if (kt < 15)
            stage_rowsR<1024, 128>(smem[cur ^ 1], (const char*)kbase + (size_t)(kt + 1) * 16384, 128, tid);
        __builtin_amdgcn_sched_barrier(0);
        const bf16* kb = smem[cur];
        f32x4 s[8];
        {
            f32x4 z = {0.f, 0.f, 0.f, 0.f};
            #pragma unroll
            for (int ni = 0; ni < 8; ++ni) s[ni] = z;
        }
        __builtin_amdgcn_s_setprio(1);
        #pragma unroll
        for (int ks = 0; ks < 2; ++ks)
            #pragma unroll
            for (int ni = 0; ni < 8; ++ni)
                s[ni] = mfma16(ldsfragR<128>(kb, ni * 16 + lr, ks * 64 + lg * 16), aq[ks], s[ni]);
        __builtin_amdgcn_s_setprio(0);
        #pragma unroll
        for (int ni = 0; ni < 8; ++ni)
            #pragma unroll
            for (int r = 0; r < 4; ++r)
                lsum += EXP2F(s[ni][r] * C2EXP);
        cur ^= 1;
    }
    lsum += __shfl_xor(lsum, 16);
    lsum += __shfl_xor(lsum, 32);
    const float l2i = -LOG2F(lsum);

    f32x4 o[4];
    {
        f32x4 z = {0.f, 0.f, 0.f, 0.f};
        #pragma unroll
        for (int ni = 0; ni < 4; ++ni) o[ni] = z;
    }
    float* attnrow = gattn + (size_t)bh * 2048 * 2048 + (size_t)(q0 + w * 16 + lr) * 2048;

    // ---- pass 2: BK=128; K in smem[cur][0..8191], V^T in smem[cur][8192..]
    stage_rowsR<1024, 128>(smem[0],        (const char*)kbase, 128, tid);
    stage_rowsR<1024, 256>(smem[0] + 8192, (const char*)vtb, 4096, tid);
    cur = 0;
    #pragma unroll 1
    for (int kt = 0; kt < 16; ++kt) {
        // drain the 8 staging loads; stores (8/lane, newer in FIFO) may remain
        if (kt == 0) asm volatile("s_waitcnt vmcnt(0)" ::: "memory");
        else         asm volatile("s_waitcnt vmcnt(8)" ::: "memory");
        __builtin_amdgcn_s_barrier();
        asm volatile("" ::: "memory");
        if (kt < 15) {
            stage_rowsR<1024, 128>(smem[cur ^ 1],        (const char*)kbase + (size_t)(kt + 1) * 16384, 128, tid);
            stage_rowsR<1024, 256>(smem[cur ^ 1] + 8192, (const char*)vtb + (size_t)(kt + 1) * 256, 4096, tid);
        }
        __builtin_amdgcn_sched_barrier(0);   // keep staging issue ahead of compute/stores
        const bf16* kb = smem[cur];
        const bf16* vb = smem[cur] + 8192;
        f32x4 s[8];
        {
            f32x4 z = {0.f, 0.f, 0.f, 0.f};
            #pragma unroll
            for (int ni = 0; ni < 8; ++ni) s[ni] = z;
        }
        __builtin_amdgcn_s_setprio(1);
        #pragma unroll
        for (int ks = 0; ks < 2; ++ks)
            #pragma unroll
            for (int ni = 0; ni < 8; ++ni)
                s[ni] = mfma16(ldsfragR<128>(kb, ni * 16 + lr, ks * 64 + lg * 16), aq[ks], s[ni]);
        __builtin_amdgcn_s_setprio(0);
        bf16* pl = &p_lds[w][0];
        float* arow = attnrow + kt * 128;
        #pragma unroll
        for (int ni = 0; ni < 8; ++ni) {
            f32x4 p;
            #pragma unroll
            for (int r = 0; r < 4; ++r) p[r] = EXP2F(fmaf(s[ni][r], C2EXP, l2i));
            __builtin_nontemporal_store(p, (f32x4*)(arow + ni * 16 + lg * 4));  // nt dwordx4
            bf16x4v pb;
            #pragma unroll
            for (int r = 0; r < 4; ++r) pb[r] = (bf16)p[r];
            *(bf16x4v*)((char*)pl + lr * 256 + ((ni * 32 + lg * 8) ^ ((lr & 7) << 4))) = pb;
        }
        __builtin_amdgcn_s_setprio(1);
        #pragma unroll
        for (int ks = 0; ks < 4; ++ks) {
            bf16x8 pa = ldsfragR<256>(pl, lr, ks * 64 + lg * 16);
            #pragma unroll
            for (int ni = 0; ni < 4; ++ni)
                o[ni] = mfma16(pa, ldsfragR<256>(vb, ni * 16 + lr, ks * 64 + lg * 16), o[ni]);
        }
        __builtin_amdgcn_s_setprio(0);
        cur ^= 1;
    }

    #pragma unroll
    for (int ni = 0; ni < 4; ++ni) {
        #pragma unroll
        for (int r = 0; r < 4; ++r) {
            int qr = q0 + w * 16 + lg * 4 + r;
            size_t rg = (size_t)b * 2048 + qr;
            int c = h * 64 + ni * 16 + lr;
            xcat[rg * 640 + c] = (bf16)o[ni][r];
        }
    }
}

// ---- out GEMM (BM=64 for occupancy: 320 blocks): d_out = xcat @ W_out + b_out
__global__ void __launch_bounds__(256) k_gemm_out(
    const bf16* __restrict__ X, const bf16* __restrict__ BT,
    const float* __restrict__ bout, float* __restrict__ out0)
{
    __shared__ __align__(16) bf16 lds[2 * (4096 + 8192)];   // 48 KB
    const int m0 = blockIdx.x * 64, n0 = blockIdx.y * 128;
    f32x4 acc[2][4];
    {
        f32x4 z = {0.f, 0.f, 0.f, 0.f};
        #pragma unroll
        for (int mi = 0; mi < 2; ++mi)
            #pragma unroll
            for (int ni = 0; ni < 4; ++ni) acc[mi][ni] = z;
    }
    gemm_main<2>(X, BT, m0, n0, lds, acc);

    const int tid = threadIdx.x, w = tid >> 6, lane = tid & 63;
    const int lr = lane & 15, lg = lane >> 4;
    const int wm = (w >> 1) * 32, wn = (w & 1) * 64;
    #pragma unroll
    for (int mi = 0; mi < 2; ++mi)
        #pragma unroll
        for (int ni = 0; ni < 4; ++ni) {
            int n = n0 + wn + ni * 16 + lr;
            float bv = bout[n];
            #pragma unroll
            for (int r = 0; r < 4; ++r) {
                int rg = m0 + wm + mi * 16 + lg * 4 + r;
                out0[(size_t)rg * 640 + n] = acc[mi][ni][r] + bv;
            }
        }
}

extern "C" void kernel_launch(void* const* d_in, const int* in_sizes, int n_in,
                              void* d_out, int out_size, void* d_ws, size_t ws_size,
                              hipStream_t stream)
{
    (void)in_sizes; (void)n_in; (void)out_size; (void)ws_size;
    const float* Q    = (const float*)d_in[0];
    const float* WQ   = (const float*)d_in[1];
    const float* bQ   = (const float*)d_in[2];
    const float* WK   = (const float*)d_in[3];
    const float* bK   = (const float*)d_in[4];
    const float* WV   = (const float*)d_in[5];
    const float* bV   = (const float*)d_in[6];
    const float* Wpos = (const float*)d_in[7];
    const float* Wagg = (const float*)d_in[8];
    const float* bagg = (const float*)d_in[9];
    const float* WO   = (const float*)d_in[10];
    const float* bout = (const float*)d_in[11];

    float* out0  = (float*)d_out;
    float* gattn = out0 + (size_t)MROWS * DIMN;   // attn output region (268 MB)

    char* ws = (char*)d_ws;
    bf16* Qbf    = (bf16*)(ws);                 ws += (size_t)MROWS * DIMN * 2;      // 5.24 MB
    bf16* BTqkv  = (bf16*)(ws);                 ws += (size_t)1920 * 640 * 2;        // 2.46 MB
    bf16* BTout  = (bf16*)(ws);                 ws += (size_t)640 * 640 * 2;         // 0.82 MB
    bf16* qsbuf  = (bf16*)(ws);                 ws += (size_t)4 * 8 * 2048 * 64 * 2; // 8 MB (q+k)
    bf16* vsT    = (bf16*)(ws);                 ws += (size_t)16 * 64 * 2048 * 2;    // 4 MB
    float* aggbuf= (float*)(ws);                ws += (size_t)3 * MROWS * AGGD * 4;  // 6 MB
    bf16* xcat   = (bf16*)(ws);                 ws += (size_t)MROWS * DIMN * 2;      // 5.24 MB

    k_split_q<<<dim3(2560), dim3(256), 0, stream>>>(Q, Qbf);
    k_prep_w<<<dim3(100, 4), dim3(256), 0, stream>>>(WQ, WK, WV, WO, BTqkv, BTout);
    k_gemm_qkv<<<dim3(32, 15), dim3(256), 0, stream>>>(Qbf, BTqkv,
                                                       bQ, bK, bV, Wpos, qsbuf, vsT, aggbuf);
    k_agg<<<dim3(128), dim3(256), 0, stream>>>(aggbuf, Wagg, bagg, xcat);
    k_attn<<<dim3(32, 16), dim3(256), 0, stream>>>(qsbuf, vsT, gattn, xcat);
    k_gemm_out<<<dim3(64, 5), dim3(256), 0, stream>>>(xcat, BTout, bout, out0);
}

// Round 12
// 163.211 us; speedup vs baseline: 1.1133x; 1.0679x over previous
//
#include <hip/hip_runtime.h>
#include <cstdint>
#include <cstddef>

// Problem constants
#define BSZ   2
#define QL    2048
#define DIMN  640
#define NH    8
#define CMAIN 512
#define AGGD  128
#define MROWS 4096                 // BSZ*QL
#define SCALE_QK 0.11180339887498948f   // (DIM/NHEADS)^-0.5 = 80^-0.5
#define C2EXP (SCALE_QK * 1.4426950408889634f)   // scale * log2(e)

typedef __bf16 bf16;
typedef __bf16 bf16x8 __attribute__((ext_vector_type(8)));
typedef __bf16 bf16x4v __attribute__((ext_vector_type(4)));
typedef float  f32x4  __attribute__((ext_vector_type(4)));

typedef __attribute__((address_space(1))) const uint32_t GU32;
typedef __attribute__((address_space(3))) uint32_t LU32;
#define GLL(g, l) __builtin_amdgcn_global_load_lds((GU32*)(g), (LU32*)(l), 16, 0, 0)

// hardware transcendentals (base-2): v_exp_f32 / v_log_f32
#define EXP2F(x) __builtin_amdgcn_exp2f(x)
#define LOG2F(x) __builtin_amdgcn_logf(x)

static __device__ __forceinline__ f32x4 mfma16(bf16x8 a, bf16x8 b, f32x4 c) {
    return __builtin_amdgcn_mfma_f32_16x16x32_bf16(a, b, c, 0, 0, 0);
}

static __device__ __forceinline__ void waitbar() {
    asm volatile("s_waitcnt vmcnt(0)" ::: "memory");
    __builtin_amdgcn_s_barrier();
    asm volatile("" ::: "memory");
}

// LDS tiles: rows of ROWB bytes, XOR-swizzled byte ^= (row&7)<<4.
// global_load_lds writes LDS linearly, so the swizzle is applied by
// inverse-swizzling the per-lane GLOBAL source address (both-sides rule #21).
template<int ROWB>
static __device__ __forceinline__ bf16x8 ldsfragR(const bf16* base, int row, int kbyte) {
    return *(const bf16x8*)((const char*)base + row * ROWB + (kbyte ^ ((row & 7) << 4)));
}

// stage NCH 16B-chunks into LDS rows of ROWB bytes from global rows of strideB.
// NT = threads in block. LDS dest is wave-uniform base; HW appends lane*16.
template<int NCH, int ROWB, int NT>
static __device__ __forceinline__ void stage_rowsN(bf16* ldsbuf, const char* gbase,
                                                   int strideB, int tid) {
    const int lane = tid & 63;
    const int wbase = tid - lane;
    #pragma unroll
    for (int i = 0; i < NCH / NT; ++i) {
        int c = i * NT + tid;
        int r = c / (ROWB / 16);
        int kb = ((c % (ROWB / 16)) * 16) ^ ((r & 7) << 4);   // inverse-swizzled
        GLL(gbase + (size_t)r * strideB + kb,
            (char*)ldsbuf + (size_t)(i * NT + wbase) * 16);
    }
}

// Plain-bf16 GEMM mainloop (fp32 MFMA accumulate). C = A*B; A [M][640] bf16,
// B^T [n][k=640] bf16. Block tile (MI*32)x128, 4 waves 2x2. Double-buffered,
// 1 barrier per 64-K chunk, 10 chunks.
template<int MI>
static __device__ __forceinline__ void gemm_main(
    const bf16* __restrict__ A, const bf16* __restrict__ BT,
    int m0, int n0, bf16* lds, f32x4 acc[MI][4])
{
    const int tid = threadIdx.x;
    const int w = tid >> 6, lane = tid & 63;
    const int lr = lane & 15, lg = lane >> 4;
    const int wm = (w >> 1) * (MI * 16), wn = (w & 1) * 64;
    constexpr int ASZ = MI * 2048;          // A-tile bf16 elems (MI*32 rows x 64)
    constexpr int BUF = ASZ + 8192;

    stage_rowsN<MI * 256, 128, 256>(lds,   (const char*)(A + (size_t)m0 * 640), 1280, tid);
    stage_rowsN<1024, 128, 256>(lds + ASZ, (const char*)(BT + (size_t)n0 * 640), 1280, tid);
    int cur = 0;
    #pragma unroll 1
    for (int ch = 0; ch < 10; ++ch) {
        waitbar();
        if (ch < 9) {
            int kk = (ch + 1) * 64;
            bf16* nb = lds + (cur ^ 1) * BUF;
            stage_rowsN<MI * 256, 128, 256>(nb,   (const char*)(A + (size_t)m0 * 640 + kk), 1280, tid);
            stage_rowsN<1024, 128, 256>(nb + ASZ, (const char*)(BT + (size_t)n0 * 640 + kk), 1280, tid);
        }
        const bf16* cA = lds + cur * BUF;
        const bf16* cB = cA + ASZ;
        #pragma unroll
        for (int ks = 0; ks < 2; ++ks) {
            bf16x8 a[MI], b[4];
            #pragma unroll
            for (int i = 0; i < MI; ++i) a[i] = ldsfragR<128>(cA, wm + i * 16 + lr, ks * 64 + lg * 16);
            #pragma unroll
            for (int i = 0; i < 4; ++i)  b[i] = ldsfragR<128>(cB, wn + i * 16 + lr, ks * 64 + lg * 16);
            #pragma unroll
            for (int mi = 0; mi < MI; ++mi)
                #pragma unroll
                for (int ni = 0; ni < 4; ++ni)
                    acc[mi][ni] = mfma16(a[mi], b[ni], acc[mi][ni]);
        }
        cur ^= 1;
    }
}

// ---- prep: Q (4096x640 f32) -> bf16 ----
__global__ void __launch_bounds__(256) k_split_q(const float* __restrict__ Q,
                                                 bf16* __restrict__ Qbf) {
    int i = blockIdx.x * 256 + threadIdx.x;
    float4 v = ((const float4*)Q)[i];
    bf16x4v hv;
    hv[0] = (bf16)v.x; hv[1] = (bf16)v.y; hv[2] = (bf16)v.z; hv[3] = (bf16)v.w;
    *(bf16x4v*)(Qbf + (size_t)i * 4) = hv;
}

// ---- prep: coalesced LDS-transpose of W_Q/W_K/W_V/W_out into B^T bf16.
__global__ void __launch_bounds__(256) k_prep_w(
    const float* __restrict__ WQ, const float* __restrict__ WK,
    const float* __restrict__ WV, const float* __restrict__ WO,
    bf16* __restrict__ BTqkv, bf16* __restrict__ BTout)
{
    __shared__ float tl[64][65];     // tl[n_loc][k_loc]
    const int ty = blockIdx.x / 10, tx = blockIdx.x % 10;
    const int wsel = blockIdx.y;
    const float* W = (wsel == 0) ? WQ : (wsel == 1) ? WK : (wsel == 2) ? WV : WO;
    const int tid = threadIdx.x;
    const int rr = tid >> 4;             // k row group 0..15
    const int cc = (tid & 15) * 4;       // n col 0..60
    #pragma unroll
    for (int i = 0; i < 4; ++i) {
        int k = tx * 64 + rr + i * 16;
        float4 v = *(const float4*)(W + (size_t)k * 640 + ty * 64 + cc);
        tl[cc + 0][rr + i * 16] = v.x;
        tl[cc + 1][rr + i * 16] = v.y;
        tl[cc + 2][rr + i * 16] = v.z;
        tl[cc + 3][rr + i * 16] = v.w;
    }
    __syncthreads();
    bf16* dst; int nbase;
    if (wsel < 3) { dst = BTqkv; nbase = wsel * 640 + ty * 64; }
    else          { dst = BTout; nbase = ty * 64; }
    const int nl0 = tid >> 4;
    const int kl = (tid & 15) * 4;
    #pragma unroll
    for (int i = 0; i < 4; ++i) {
        int nl = nl0 + i * 16;
        bf16x4v hv;
        #pragma unroll
        for (int j = 0; j < 4; ++j) hv[j] = (bf16)tl[nl][kl + j];
        *(bf16x4v*)(dst + (size_t)(nbase + nl) * 640 + tx * 64 + kl) = hv;
    }
}

// ---- QKV GEMM: C[4096][1920] ; epilogue adds bias (+W_pos) and routes outputs
__global__ void __launch_bounds__(256) k_gemm_qkv(
    const bf16* __restrict__ Qbf, const bf16* __restrict__ BT,
    const float* __restrict__ bQ, const float* __restrict__ bK, const float* __restrict__ bV,
    const float* __restrict__ Wpos,
    bf16* __restrict__ qsbuf, bf16* __restrict__ vsT, float* __restrict__ aggbuf)
{
    __shared__ __align__(16) bf16 lds[2 * (8192 + 8192)];   // 64 KB
    const int m0 = blockIdx.x * 128, n0 = blockIdx.y * 128;
    f32x4 acc[4][4];
    {
        f32x4 z = {0.f, 0.f, 0.f, 0.f};
        #pragma unroll
        for (int mi = 0; mi < 4; ++mi)
            #pragma unroll
            for (int ni = 0; ni < 4; ++ni) acc[mi][ni] = z;
    }
    gemm_main<4>(Qbf, BT, m0, n0, lds, acc);

    const int tid = threadIdx.x, w = tid >> 6, lane = tid & 63;
    const int lr = lane & 15, lg = lane >> 4;
    const int wm = (w >> 1) * 64, wn = (w & 1) * 64;
    const int p = n0 / 640;                       // block-uniform (640 % 128 == 0)
    const float* bias = (p == 0) ? bQ : (p == 1) ? bK : bV;

    #pragma unroll
    for (int mi = 0; mi < 4; ++mi)
        #pragma unroll
        for (int ni = 0; ni < 4; ++ni) {
            int n = n0 + wn + ni * 16 + lr;
            int c = n - p * 640;
            int rbase = m0 + wm + mi * 16 + lg * 4;
            float bval = bias[c];
            if (c < 512) {
                int hh = c >> 6, d = c & 63;
                #pragma unroll
                for (int r = 0; r < 4; ++r) {
                    int rg = rbase + r;
                    int bb = rg >> 11, l = rg & 2047;
                    float v = acc[mi][ni][r] + bval + Wpos[(size_t)l * 512 + c];
                    if (p < 2)
                        qsbuf[(((size_t)(p * 2 + bb) * 8 + hh) * 2048 + l) * 64 + d] = (bf16)v;
                    else
                        vsT[(((size_t)(bb * 8 + hh)) * 64 + d) * 2048 + l] = (bf16)v;
                }
            } else {
                int j = c - 512;
                #pragma unroll
                for (int r = 0; r < 4; ++r) {
                    int rg = rbase + r;
                    aggbuf[((size_t)p * MROWS + rg) * AGGD + j] = acc[mi][ni][r] + bval;
                }
            }
        }
}

// ---- agg: x = mean3(aggbuf) ; gelu_tanh(x @ W_agg + b_agg) -> xcat cols 512..639
__global__ void __launch_bounds__(256) k_agg(const float* __restrict__ aggbuf,
                                             const float* __restrict__ Wagg, const float* __restrict__ bagg,
                                             bf16* __restrict__ xcat)
{
    __shared__ float wl[128 * 128];
    __shared__ float xl[32 * 128];
    const int tid = threadIdx.x;
    const int r0 = blockIdx.x * 32;
    for (int i = tid; i < 128 * 128; i += 256) wl[i] = Wagg[i];
    for (int i = tid; i < 32 * 128; i += 256) {
        int row = i >> 7, j = i & 127;
        size_t rg = r0 + row;
        float s = aggbuf[rg * AGGD + j]
                + aggbuf[((size_t)MROWS + rg) * AGGD + j]
                + aggbuf[((size_t)2 * MROWS + rg) * AGGD + j];
        xl[i] = s * (1.0f / 3.0f);
    }
    __syncthreads();
    const int row = tid >> 3;
    const int jo0 = (tid & 7) * 16;
    float acc[16];
    #pragma unroll
    for (int jj = 0; jj < 16; ++jj) acc[jj] = 0.f;
    for (int j = 0; j < 128; ++j) {
        float xv = xl[row * 128 + j];
        const float* wr = &wl[j * 128 + jo0];
        #pragma unroll
        for (int jj = 0; jj < 16; ++jj) acc[jj] = fmaf(xv, wr[jj], acc[jj]);
    }
    size_t rg = r0 + row;
    #pragma unroll
    for (int jj = 0; jj < 16; ++jj) {
        float t = acc[jj] + bagg[jo0 + jj];
        float g = 0.5f * t * (1.0f + tanhf(0.7978845608028654f * (t + 0.044715f * t * t * t)));
        xcat[rg * 640 + 512 + jo0 + jj] = (bf16)g;
    }
}

// ---- attention: 8-wave blocks (512 thr), 128 q-rows, grid (16,16) = 256 blocks
// (1/CU, 96 KB LDS, 8 waves/CU — same wave count as R7, HALF the K/V re-reads).
// Per-wave code identical to R7 (16 q-rows each). NO-MAX softmax, swapped QK^T.
// pass1: BK=128; pass2: BK=128, counted vmcnt(8).
__global__ void __launch_bounds__(512) k_attn(const bf16* __restrict__ qsbuf, const bf16* __restrict__ vsT,
                                              float* __restrict__ gattn,
                                              bf16* __restrict__ xcat)
{
    __shared__ __align__(16) bf16 smem[2][16384];       // 64 KB: K[128][128B] + V[64][256B]
    __shared__ __align__(16) bf16 p_lds[8][16 * 128];   // 32 KB, per-wave [16 q][256B]

    const int bh = blockIdx.y;
    const int b = bh >> 3, h = bh & 7;
    const int q0 = blockIdx.x * 128;
    const int tid = threadIdx.x, w = tid >> 6, lane = tid & 63;
    const int lr = lane & 15, lg = lane >> 4;

    const bf16* qbase = qsbuf + (size_t)(b * 8 + h) * (2048 * 64);          // q
    const bf16* kbase = qsbuf + (size_t)((2 + b) * 8 + h) * (2048 * 64);    // k
    const bf16* vtb   = vsT + (size_t)(b * 8 + h) * (64 * 2048);

    bf16x8 aq[2];
    {
        const bf16* qp = qbase + (size_t)(q0 + w * 16 + lr) * 64 + lg * 8;
        aq[0] = *(const bf16x8*)(qp);
        aq[1] = *(const bf16x8*)(qp + 32);
    }

    // ---- pass 1: denominator sums, BK=128
    float lsum = 0.f;
    stage_rowsN<1024, 128, 512>(smem[0], (const char*)kbase, 128, tid);
    int cur = 0;
    #pragma unroll 1
    for (int kt = 0; kt < 16; ++kt) {
        waitbar();
        if (kt < 15)
            stage_rowsN<1024, 128, 512>(smem[cur ^ 1], (const char*)kbase + (size_t)(kt + 1) * 16384, 128, tid);
        __builtin_amdgcn_sched_barrier(0);
        const bf16* kb = smem[cur];
        f32x4 s[8];
        {
            f32x4 z = {0.f, 0.f, 0.f, 0.f};
            #pragma unroll
            for (int ni = 0; ni < 8; ++ni) s[ni] = z;
        }
        #pragma unroll
        for (int ks = 0; ks < 2; ++ks)
            #pragma unroll
            for (int ni = 0; ni < 8; ++ni)
                s[ni] = mfma16(ldsfragR<128>(kb, ni * 16 + lr, ks * 64 + lg * 16), aq[ks], s[ni]);
        #pragma unroll
        for (int ni = 0; ni < 8; ++ni)
            #pragma unroll
            for (int r = 0; r < 4; ++r)
                lsum += EXP2F(s[ni][r] * C2EXP);
        cur ^= 1;
    }
    lsum += __shfl_xor(lsum, 16);
    lsum += __shfl_xor(lsum, 32);
    const float l2i = -LOG2F(lsum);

    f32x4 o[4];
    {
        f32x4 z = {0.f, 0.f, 0.f, 0.f};
        #pragma unroll
        for (int ni = 0; ni < 4; ++ni) o[ni] = z;
    }
    float* attnrow = gattn + (size_t)bh * 2048 * 2048 + (size_t)(q0 + w * 16 + lr) * 2048;

    // ---- pass 2: BK=128; K in smem[cur][0..8191], V^T in smem[cur][8192..]
    stage_rowsN<1024, 128, 512>(smem[0],        (const char*)kbase, 128, tid);
    stage_rowsN<1024, 256, 512>(smem[0] + 8192, (const char*)vtb, 4096, tid);
    cur = 0;
    #pragma unroll 1
    for (int kt = 0; kt < 16; ++kt) {
        // drain the 4 staging loads; stores (8/lane, newer in FIFO) may remain
        if (kt == 0) asm volatile("s_waitcnt vmcnt(0)" ::: "memory");
        else         asm volatile("s_waitcnt vmcnt(8)" ::: "memory");
        __builtin_amdgcn_s_barrier();
        asm volatile("" ::: "memory");
        if (kt < 15) {
            stage_rowsN<1024, 128, 512>(smem[cur ^ 1],        (const char*)kbase + (size_t)(kt + 1) * 16384, 128, tid);
            stage_rowsN<1024, 256, 512>(smem[cur ^ 1] + 8192, (const char*)vtb + (size_t)(kt + 1) * 256, 4096, tid);
        }
        __builtin_amdgcn_sched_barrier(0);   // keep staging issue ahead of compute/stores
        const bf16* kb = smem[cur];
        const bf16* vb = smem[cur] + 8192;
        f32x4 s[8];
        {
            f32x4 z = {0.f, 0.f, 0.f, 0.f};
            #pragma unroll
            for (int ni = 0; ni < 8; ++ni) s[ni] = z;
        }
        #pragma unroll
        for (int ks = 0; ks < 2; ++ks)
            #pragma unroll
            for (int ni = 0; ni < 8; ++ni)
                s[ni] = mfma16(ldsfragR<128>(kb, ni * 16 + lr, ks * 64 + lg * 16), aq[ks], s[ni]);
        bf16* pl = &p_lds[w][0];
        float* arow = attnrow + kt * 128;
        #pragma unroll
        for (int ni = 0; ni < 8; ++ni) {
            f32x4 p;
            #pragma unroll
            for (int r = 0; r < 4; ++r) p[r] = EXP2F(fmaf(s[ni][r], C2EXP, l2i));
            *(f32x4*)(arow + ni * 16 + lg * 4) = p;          // dwordx4 attn store
            bf16x4v pb;
            #pragma unroll
            for (int r = 0; r < 4; ++r) pb[r] = (bf16)p[r];
            *(bf16x4v*)((char*)pl + lr * 256 + ((ni * 32 + lg * 8) ^ ((lr & 7) << 4))) = pb;
        }
        #pragma unroll
        for (int ks = 0; ks < 4; ++ks) {
            bf16x8 pa = ldsfragR<256>(pl, lr, ks * 64 + lg * 16);
            #pragma unroll
            for (int ni = 0; ni < 4; ++ni)
                o[ni] = mfma16(pa, ldsfragR<256>(vb, ni * 16 + lr, ks * 64 + lg * 16), o[ni]);
        }
        cur ^= 1;
    }

    #pragma unroll
    for (int ni = 0; ni < 4; ++ni) {
        #pragma unroll
        for (int r = 0; r < 4; ++r) {
            int qr = q0 + w * 16 + lg * 4 + r;
            size_t rg = (size_t)b * 2048 + qr;
            int c = h * 64 + ni * 16 + lr;
            xcat[rg * 640 + c] = (bf16)o[ni][r];
        }
    }
}

// ---- out GEMM (BM=64 for occupancy: 320 blocks): d_out = xcat @ W_out + b_out
__global__ void __launch_bounds__(256) k_gemm_out(
    const bf16* __restrict__ X, const bf16* __restrict__ BT,
    const float* __restrict__ bout, float* __restrict__ out0)
{
    __shared__ __align__(16) bf16 lds[2 * (4096 + 8192)];   // 48 KB
    const int m0 = blockIdx.x * 64, n0 = blockIdx.y * 128;
    f32x4 acc[2][4];
    {
        f32x4 z = {0.f, 0.f, 0.f, 0.f};
        #pragma unroll
        for (int mi = 0; mi < 2; ++mi)
            #pragma unroll
            for (int ni = 0; ni < 4; ++ni) acc[mi][ni] = z;
    }
    gemm_main<2>(X, BT, m0, n0, lds, acc);

    const int tid = threadIdx.x, w = tid >> 6, lane = tid & 63;
    const int lr = lane & 15, lg = lane >> 4;
    const int wm = (w >> 1) * 32, wn = (w & 1) * 64;
    #pragma unroll
    for (int mi = 0; mi < 2; ++mi)
        #pragma unroll
        for (int ni = 0; ni < 4; ++ni) {
            int n = n0 + wn + ni * 16 + lr;
            float bv = bout[n];
            #pragma unroll
            for (int r = 0; r < 4; ++r) {
                int rg = m0 + wm + mi * 16 + lg * 4 + r;
                out0[(size_t)rg * 640 + n] = acc[mi][ni][r] + bv;
            }
        }
}

extern "C" void kernel_launch(void* const* d_in, const int* in_sizes, int n_in,
                              void* d_out, int out_size, void* d_ws, size_t ws_size,
                              hipStream_t stream)
{
    (void)in_sizes; (void)n_in; (void)out_size; (void)ws_size;
    const float* Q    = (const float*)d_in[0];
    const float* WQ   = (const float*)d_in[1];
    const float* bQ   = (const float*)d_in[2];
    const float* WK   = (const float*)d_in[3];
    const float* bK   = (const float*)d_in[4];
    const float* WV   = (const float*)d_in[5];
    const float* bV   = (const float*)d_in[6];
    const float* Wpos = (const float*)d_in[7];
    const float* Wagg = (const float*)d_in[8];
    const float* bagg = (const float*)d_in[9];
    const float* WO   = (const float*)d_in[10];
    const float* bout = (const float*)d_in[11];

    float* out0  = (float*)d_out;
    float* gattn = out0 + (size_t)MROWS * DIMN;   // attn output region (268 MB)

    char* ws = (char*)d_ws;
    bf16* Qbf    = (bf16*)(ws);                 ws += (size_t)MROWS * DIMN * 2;      // 5.24 MB
    bf16* BTqkv  = (bf16*)(ws);                 ws += (size_t)1920 * 640 * 2;        // 2.46 MB
    bf16* BTout  = (bf16*)(ws);                 ws += (size_t)640 * 640 * 2;         // 0.82 MB
    bf16* qsbuf  = (bf16*)(ws);                 ws += (size_t)4 * 8 * 2048 * 64 * 2; // 8 MB (q+k)
    bf16* vsT    = (bf16*)(ws);                 ws += (size_t)16 * 64 * 2048 * 2;    // 4 MB
    float* aggbuf= (float*)(ws);                ws += (size_t)3 * MROWS * AGGD * 4;  // 6 MB
    bf16* xcat   = (bf16*)(ws);                 ws += (size_t)MROWS * DIMN * 2;      // 5.24 MB

    k_split_q<<<dim3(2560), dim3(256), 0, stream>>>(Q, Qbf);
    k_prep_w<<<dim3(100, 4), dim3(256), 0, stream>>>(WQ, WK, WV, WO, BTqkv, BTout);
    k_gemm_qkv<<<dim3(32, 15), dim3(256), 0, stream>>>(Qbf, BTqkv,
                                                       bQ, bK, bV, Wpos, qsbuf, vsT, aggbuf);
    k_agg<<<dim3(128), dim3(256), 0, stream>>>(aggbuf, Wagg, bagg, xcat);
    k_attn<<<dim3(16, 16), dim3(512), 0, stream>>>(qsbuf, vsT, gattn, xcat);
    k_gemm_out<<<dim3(64, 5), dim3(256), 0, stream>>>(xcat, BTout, bout, out0);
}

// Round 13
// 161.417 us; speedup vs baseline: 1.1257x; 1.0111x over previous
//
#include <hip/hip_runtime.h>
#include <cstdint>
#include <cstddef>

// Problem constants
#define BSZ   2
#define QL    2048
#define DIMN  640
#define NH    8
#define CMAIN 512
#define AGGD  128
#define MROWS 4096                 // BSZ*QL
#define SCALE_QK 0.11180339887498948f   // (DIM/NHEADS)^-0.5 = 80^-0.5
#define C2EXP (SCALE_QK * 1.4426950408889634f)   // scale * log2(e)

typedef __bf16 bf16;
typedef __bf16 bf16x8 __attribute__((ext_vector_type(8)));
typedef __bf16 bf16x4v __attribute__((ext_vector_type(4)));
typedef float  f32x4  __attribute__((ext_vector_type(4)));

typedef __attribute__((address_space(1))) const uint32_t GU32;
typedef __attribute__((address_space(3))) uint32_t LU32;
#define GLL(g, l) __builtin_amdgcn_global_load_lds((GU32*)(g), (LU32*)(l), 16, 0, 0)

// hardware transcendentals (base-2): v_exp_f32 / v_log_f32
#define EXP2F(x) __builtin_amdgcn_exp2f(x)
#define LOG2F(x) __builtin_amdgcn_logf(x)

static __device__ __forceinline__ f32x4 mfma16(bf16x8 a, bf16x8 b, f32x4 c) {
    return __builtin_amdgcn_mfma_f32_16x16x32_bf16(a, b, c, 0, 0, 0);
}

static __device__ __forceinline__ void waitbar() {
    asm volatile("s_waitcnt vmcnt(0)" ::: "memory");
    __builtin_amdgcn_s_barrier();
    asm volatile("" ::: "memory");
}

// LDS tiles: rows of ROWB bytes, XOR-swizzled byte ^= (row&7)<<4.
// global_load_lds writes LDS linearly, so the swizzle is applied by
// inverse-swizzling the per-lane GLOBAL source address (both-sides rule #21).
template<int ROWB>
static __device__ __forceinline__ bf16x8 ldsfragR(const bf16* base, int row, int kbyte) {
    return *(const bf16x8*)((const char*)base + row * ROWB + (kbyte ^ ((row & 7) << 4)));
}

// stage NCH 16B-chunks into LDS rows of ROWB bytes from global rows of strideB.
// NT = threads in block. LDS dest is wave-uniform base; HW appends lane*16.
template<int NCH, int ROWB, int NT>
static __device__ __forceinline__ void stage_rowsN(bf16* ldsbuf, const char* gbase,
                                                   int strideB, int tid) {
    const int lane = tid & 63;
    const int wbase = tid - lane;
    #pragma unroll
    for (int i = 0; i < NCH / NT; ++i) {
        int c = i * NT + tid;
        int r = c / (ROWB / 16);
        int kb = ((c % (ROWB / 16)) * 16) ^ ((r & 7) << 4);   // inverse-swizzled
        GLL(gbase + (size_t)r * strideB + kb,
            (char*)ldsbuf + (size_t)(i * NT + wbase) * 16);
    }
}

// Plain-bf16 GEMM mainloop (fp32 MFMA accumulate). C = A*B; A [M][640] bf16,
// B^T [n][k=640] bf16. Block tile (MI*32)x128, 4 waves 2x2. Double-buffered,
// 1 barrier per 64-K chunk, 10 chunks.
template<int MI>
static __device__ __forceinline__ void gemm_main(
    const bf16* __restrict__ A, const bf16* __restrict__ BT,
    int m0, int n0, bf16* lds, f32x4 acc[MI][4])
{
    const int tid = threadIdx.x;
    const int w = tid >> 6, lane = tid & 63;
    const int lr = lane & 15, lg = lane >> 4;
    const int wm = (w >> 1) * (MI * 16), wn = (w & 1) * 64;
    constexpr int ASZ = MI * 2048;          // A-tile bf16 elems (MI*32 rows x 64)
    constexpr int BUF = ASZ + 8192;

    stage_rowsN<MI * 256, 128, 256>(lds,   (const char*)(A + (size_t)m0 * 640), 1280, tid);
    stage_rowsN<1024, 128, 256>(lds + ASZ, (const char*)(BT + (size_t)n0 * 640), 1280, tid);
    int cur = 0;
    #pragma unroll 1
    for (int ch = 0; ch < 10; ++ch) {
        waitbar();
        if (ch < 9) {
            int kk = (ch + 1) * 64;
            bf16* nb = lds + (cur ^ 1) * BUF;
            stage_rowsN<MI * 256, 128, 256>(nb,   (const char*)(A + (size_t)m0 * 640 + kk), 1280, tid);
            stage_rowsN<1024, 128, 256>(nb + ASZ, (const char*)(BT + (size_t)n0 * 640 + kk), 1280, tid);
        }
        const bf16* cA = lds + cur * BUF;
        const bf16* cB = cA + ASZ;
        #pragma unroll
        for (int ks = 0; ks < 2; ++ks) {
            bf16x8 a[MI], b[4];
            #pragma unroll
            for (int i = 0; i < MI; ++i) a[i] = ldsfragR<128>(cA, wm + i * 16 + lr, ks * 64 + lg * 16);
            #pragma unroll
            for (int i = 0; i < 4; ++i)  b[i] = ldsfragR<128>(cB, wn + i * 16 + lr, ks * 64 + lg * 16);
            #pragma unroll
            for (int mi = 0; mi < MI; ++mi)
                #pragma unroll
                for (int ni = 0; ni < 4; ++ni)
                    acc[mi][ni] = mfma16(a[mi], b[ni], acc[mi][ni]);
        }
        cur ^= 1;
    }
}

// ---- prep: Q (4096x640 f32) -> bf16 ----
__global__ void __launch_bounds__(256) k_split_q(const float* __restrict__ Q,
                                                 bf16* __restrict__ Qbf) {
    int i = blockIdx.x * 256 + threadIdx.x;
    float4 v = ((const float4*)Q)[i];
    bf16x4v hv;
    hv[0] = (bf16)v.x; hv[1] = (bf16)v.y; hv[2] = (bf16)v.z; hv[3] = (bf16)v.w;
    *(bf16x4v*)(Qbf + (size_t)i * 4) = hv;
}

// ---- prep: coalesced LDS-transpose of W_Q/W_K/W_V/W_out into B^T bf16.
__global__ void __launch_bounds__(256) k_prep_w(
    const float* __restrict__ WQ, const float* __restrict__ WK,
    const float* __restrict__ WV, const float* __restrict__ WO,
    bf16* __restrict__ BTqkv, bf16* __restrict__ BTout)
{
    __shared__ float tl[64][65];     // tl[n_loc][k_loc]
    const int ty = blockIdx.x / 10, tx = blockIdx.x % 10;
    const int wsel = blockIdx.y;
    const float* W = (wsel == 0) ? WQ : (wsel == 1) ? WK : (wsel == 2) ? WV : WO;
    const int tid = threadIdx.x;
    const int rr = tid >> 4;             // k row group 0..15
    const int cc = (tid & 15) * 4;       // n col 0..60
    #pragma unroll
    for (int i = 0; i < 4; ++i) {
        int k = tx * 64 + rr + i * 16;
        float4 v = *(const float4*)(W + (size_t)k * 640 + ty * 64 + cc);
        tl[cc + 0][rr + i * 16] = v.x;
        tl[cc + 1][rr + i * 16] = v.y;
        tl[cc + 2][rr + i * 16] = v.z;
        tl[cc + 3][rr + i * 16] = v.w;
    }
    __syncthreads();
    bf16* dst; int nbase;
    if (wsel < 3) { dst = BTqkv; nbase = wsel * 640 + ty * 64; }
    else          { dst = BTout; nbase = ty * 64; }
    const int nl0 = tid >> 4;
    const int kl = (tid & 15) * 4;
    #pragma unroll
    for (int i = 0; i < 4; ++i) {
        int nl = nl0 + i * 16;
        bf16x4v hv;
        #pragma unroll
        for (int j = 0; j < 4; ++j) hv[j] = (bf16)tl[nl][kl + j];
        *(bf16x4v*)(dst + (size_t)(nbase + nl) * 640 + tx * 64 + kl) = hv;
    }
}

// ---- QKV GEMM: C[4096][1920] ; epilogue adds bias (+W_pos) and routes outputs
__global__ void __launch_bounds__(256) k_gemm_qkv(
    const bf16* __restrict__ Qbf, const bf16* __restrict__ BT,
    const float* __restrict__ bQ, const float* __restrict__ bK, const float* __restrict__ bV,
    const float* __restrict__ Wpos,
    bf16* __restrict__ qsbuf, bf16* __restrict__ vsT, float* __restrict__ aggbuf)
{
    __shared__ __align__(16) bf16 lds[2 * (8192 + 8192)];   // 64 KB
    const int m0 = blockIdx.x * 128, n0 = blockIdx.y * 128;
    f32x4 acc[4][4];
    {
        f32x4 z = {0.f, 0.f, 0.f, 0.f};
        #pragma unroll
        for (int mi = 0; mi < 4; ++mi)
            #pragma unroll
            for (int ni = 0; ni < 4; ++ni) acc[mi][ni] = z;
    }
    gemm_main<4>(Qbf, BT, m0, n0, lds, acc);

    const int tid = threadIdx.x, w = tid >> 6, lane = tid & 63;
    const int lr = lane & 15, lg = lane >> 4;
    const int wm = (w >> 1) * 64, wn = (w & 1) * 64;
    const int p = n0 / 640;                       // block-uniform (640 % 128 == 0)
    const float* bias = (p == 0) ? bQ : (p == 1) ? bK : bV;

    #pragma unroll
    for (int mi = 0; mi < 4; ++mi)
        #pragma unroll
        for (int ni = 0; ni < 4; ++ni) {
            int n = n0 + wn + ni * 16 + lr;
            int c = n - p * 640;
            int rbase = m0 + wm + mi * 16 + lg * 4;
            float bval = bias[c];
            if (c < 512) {
                int hh = c >> 6, d = c & 63;
                #pragma unroll
                for (int r = 0; r < 4; ++r) {
                    int rg = rbase + r;
                    int bb = rg >> 11, l = rg & 2047;
                    float v = acc[mi][ni][r] + bval + Wpos[(size_t)l * 512 + c];
                    if (p < 2)
                        qsbuf[(((size_t)(p * 2 + bb) * 8 + hh) * 2048 + l) * 64 + d] = (bf16)v;
                    else
                        vsT[(((size_t)(bb * 8 + hh)) * 64 + d) * 2048 + l] = (bf16)v;
                }
            } else {
                int j = c - 512;
                #pragma unroll
                for (int r = 0; r < 4; ++r) {
                    int rg = rbase + r;
                    aggbuf[((size_t)p * MROWS + rg) * AGGD + j] = acc[mi][ni][r] + bval;
                }
            }
        }
}

// ---- agg: x = mean3(aggbuf) ; gelu_tanh(x @ W_agg + b_agg) -> xcat cols 512..639
__global__ void __launch_bounds__(256) k_agg(const float* __restrict__ aggbuf,
                                             const float* __restrict__ Wagg, const float* __restrict__ bagg,
                                             bf16* __restrict__ xcat)
{
    __shared__ float wl[128 * 128];
    __shared__ float xl[32 * 128];
    const int tid = threadIdx.x;
    const int r0 = blockIdx.x * 32;
    for (int i = tid; i < 128 * 128; i += 256) wl[i] = Wagg[i];
    for (int i = tid; i < 32 * 128; i += 256) {
        int row = i >> 7, j = i & 127;
        size_t rg = r0 + row;
        float s = aggbuf[rg * AGGD + j]
                + aggbuf[((size_t)MROWS + rg) * AGGD + j]
                + aggbuf[((size_t)2 * MROWS + rg) * AGGD + j];
        xl[i] = s * (1.0f / 3.0f);
    }
    __syncthreads();
    const int row = tid >> 3;
    const int jo0 = (tid & 7) * 16;
    float acc[16];
    #pragma unroll
    for (int jj = 0; jj < 16; ++jj) acc[jj] = 0.f;
    for (int j = 0; j < 128; ++j) {
        float xv = xl[row * 128 + j];
        const float* wr = &wl[j * 128 + jo0];
        #pragma unroll
        for (int jj = 0; jj < 16; ++jj) acc[jj] = fmaf(xv, wr[jj], acc[jj]);
    }
    size_t rg = r0 + row;
    #pragma unroll
    for (int jj = 0; jj < 16; ++jj) {
        float t = acc[jj] + bagg[jo0 + jj];
        float g = 0.5f * t * (1.0f + tanhf(0.7978845608028654f * (t + 0.044715f * t * t * t)));
        xcat[rg * 640 + 512 + jo0 + jj] = (bf16)g;
    }
}

// ---- attention: R7 structure (4 waves, 64 q-rows, grid (32,16)) with a
// DEPTH-2 prefetch pipeline (3 LDS buffers): tile k+2's loads are issued at
// iter k, so each load has two compute-tiles of latency slack (T4: counted
// vmcnt, never drain to 0 mid-loop). 56 KB LDS -> 2 blocks/CU.
// pass1: BK=128 (16 tiles); pass2: BK=64 (32 tiles).
__global__ void __launch_bounds__(256) k_attn(const bf16* __restrict__ qsbuf, const bf16* __restrict__ vsT,
                                              float* __restrict__ gattn,
                                              bf16* __restrict__ xcat)
{
    __shared__ __align__(16) bf16 smem[3][8192];     // 48 KB: 3-deep pipeline
    __shared__ __align__(16) bf16 p_lds[4][1024];    // 8 KB, per-wave [16 q][128B]

    const int bh = blockIdx.y;
    const int b = bh >> 3, h = bh & 7;
    const int q0 = blockIdx.x * 64;
    const int tid = threadIdx.x, w = tid >> 6, lane = tid & 63;
    const int lr = lane & 15, lg = lane >> 4;

    const bf16* qbase = qsbuf + (size_t)(b * 8 + h) * (2048 * 64);          // q
    const bf16* kbase = qsbuf + (size_t)((2 + b) * 8 + h) * (2048 * 64);    // k
    const bf16* vtb   = vsT + (size_t)(b * 8 + h) * (64 * 2048);

    bf16x8 aq[2];
    {
        const bf16* qp = qbase + (size_t)(q0 + w * 16 + lr) * 64 + lg * 8;
        aq[0] = *(const bf16x8*)(qp);
        aq[1] = *(const bf16x8*)(qp + 32);
    }

    // ---- pass 1: denominator sums, BK=128 (16 tiles), depth-2 prefetch.
    // loads/lane/tile = 4. Entry kt: {L_kt, L_kt+1} in flight -> vmcnt(4)
    // drains exactly L_kt (vmcnt(0) on the last tile: nothing newer).
    float lsum = 0.f;
    stage_rowsN<1024, 128, 256>(smem[0], (const char*)kbase, 128, tid);
    stage_rowsN<1024, 128, 256>(smem[1], (const char*)kbase + 16384, 128, tid);
    #pragma unroll 1
    for (int kt = 0; kt < 16; ++kt) {
        if (kt < 15) asm volatile("s_waitcnt vmcnt(4)" ::: "memory");
        else         asm volatile("s_waitcnt vmcnt(0)" ::: "memory");
        __builtin_amdgcn_s_barrier();
        asm volatile("" ::: "memory");
        if (kt < 14)
            stage_rowsN<1024, 128, 256>(smem[(kt + 2) % 3],
                                        (const char*)kbase + (size_t)(kt + 2) * 16384, 128, tid);
        __builtin_amdgcn_sched_barrier(0);
        const bf16* kb = smem[kt % 3];
        f32x4 s[8];
        {
            f32x4 z = {0.f, 0.f, 0.f, 0.f};
            #pragma unroll
            for (int ni = 0; ni < 8; ++ni) s[ni] = z;
        }
        #pragma unroll
        for (int ks = 0; ks < 2; ++ks)
            #pragma unroll
            for (int ni = 0; ni < 8; ++ni)
                s[ni] = mfma16(ldsfragR<128>(kb, ni * 16 + lr, ks * 64 + lg * 16), aq[ks], s[ni]);
        #pragma unroll
        for (int ni = 0; ni < 8; ++ni)
            #pragma unroll
            for (int r = 0; r < 4; ++r)
                lsum += EXP2F(s[ni][r] * C2EXP);
    }
    __syncthreads();   // all waves done reading smem before pass-2 prologue staging
    lsum += __shfl_xor(lsum, 16);
    lsum += __shfl_xor(lsum, 32);
    const float l2i = -LOG2F(lsum);

    f32x4 o[4];
    {
        f32x4 z = {0.f, 0.f, 0.f, 0.f};
        #pragma unroll
        for (int ni = 0; ni < 4; ++ni) o[ni] = z;
    }
    float* attnrow = gattn + (size_t)bh * 2048 * 2048 + (size_t)(q0 + w * 16 + lr) * 2048;

    // ---- pass 2: BK=64 (32 tiles), depth-2; each buf: K [0..4095], V^T [4096..]
    // loads/lane/tile = 4, stores/lane/tile = 4.
    // Entry kt FIFO (oldest->newest): L_kt, S_kt-2, L_kt+1, S_kt-1 = 16
    //  -> vmcnt(12) drains exactly L_kt.  kt=0: {L0,L1}=8 -> vmcnt(4);
    //  kt=1: {L1,L2,S0}=12 -> vmcnt(8);  kt=31: {L31,S29,S30}=12 -> vmcnt(8).
    stage_rowsN<512, 128, 256>(smem[0],        (const char*)kbase, 128, tid);
    stage_rowsN<512, 128, 256>(smem[0] + 4096, (const char*)vtb, 4096, tid);
    stage_rowsN<512, 128, 256>(smem[1],        (const char*)kbase + 8192, 128, tid);
    stage_rowsN<512, 128, 256>(smem[1] + 4096, (const char*)vtb + 128, 4096, tid);
    #pragma unroll 1
    for (int kt = 0; kt < 32; ++kt) {
        if (kt == 0)       asm volatile("s_waitcnt vmcnt(4)" ::: "memory");
        else if (kt == 1)  asm volatile("s_waitcnt vmcnt(8)" ::: "memory");
        else if (kt == 31) asm volatile("s_waitcnt vmcnt(8)" ::: "memory");
        else               asm volatile("s_waitcnt vmcnt(12)" ::: "memory");
        __builtin_amdgcn_s_barrier();
        asm volatile("" ::: "memory");
        if (kt < 30) {
            bf16* nb = smem[(kt + 2) % 3];
            stage_rowsN<512, 128, 256>(nb,        (const char*)kbase + (size_t)(kt + 2) * 8192, 128, tid);
            stage_rowsN<512, 128, 256>(nb + 4096, (const char*)vtb + (size_t)(kt + 2) * 128, 4096, tid);
        }
        __builtin_amdgcn_sched_barrier(0);   // keep staging issue ahead of compute/stores
        const bf16* kb = smem[kt % 3];
        const bf16* vb = kb + 4096;
        f32x4 s[4];
        {
            f32x4 z = {0.f, 0.f, 0.f, 0.f};
            #pragma unroll
            for (int ni = 0; ni < 4; ++ni) s[ni] = z;
        }
        #pragma unroll
        for (int ks = 0; ks < 2; ++ks)
            #pragma unroll
            for (int ni = 0; ni < 4; ++ni)
                s[ni] = mfma16(ldsfragR<128>(kb, ni * 16 + lr, ks * 64 + lg * 16), aq[ks], s[ni]);
        bf16* pl = &p_lds[w][0];
        float* arow = attnrow + kt * 64;
        #pragma unroll
        for (int ni = 0; ni < 4; ++ni) {
            f32x4 p;
            #pragma unroll
            for (int r = 0; r < 4; ++r) p[r] = EXP2F(fmaf(s[ni][r], C2EXP, l2i));
            *(f32x4*)(arow + ni * 16 + lg * 4) = p;          // dwordx4 attn store
            bf16x4v pb;
            #pragma unroll
            for (int r = 0; r < 4; ++r) pb[r] = (bf16)p[r];
            *(bf16x4v*)((char*)pl + lr * 128 + ((ni * 32 + lg * 8) ^ ((lr & 7) << 4))) = pb;
        }
        // p_lds[w] is wave-private: same-wave ds ordering via lgkmcnt only.
        #pragma unroll
        for (int ks = 0; ks < 2; ++ks) {
            bf16x8 pa = ldsfragR<128>(pl, lr, ks * 64 + lg * 16);
            #pragma unroll
            for (int ni = 0; ni < 4; ++ni)
                o[ni] = mfma16(pa, ldsfragR<128>(vb, ni * 16 + lr, ks * 64 + lg * 16), o[ni]);
        }
    }

    #pragma unroll
    for (int ni = 0; ni < 4; ++ni) {
        #pragma unroll
        for (int r = 0; r < 4; ++r) {
            int qr = q0 + w * 16 + lg * 4 + r;
            size_t rg = (size_t)b * 2048 + qr;
            int c = h * 64 + ni * 16 + lr;
            xcat[rg * 640 + c] = (bf16)o[ni][r];
        }
    }
}

// ---- out GEMM (BM=64 for occupancy: 320 blocks): d_out = xcat @ W_out + b_out
__global__ void __launch_bounds__(256) k_gemm_out(
    const bf16* __restrict__ X, const bf16* __restrict__ BT,
    const float* __restrict__ bout, float* __restrict__ out0)
{
    __shared__ __align__(16) bf16 lds[2 * (4096 + 8192)];   // 48 KB
    const int m0 = blockIdx.x * 64, n0 = blockIdx.y * 128;
    f32x4 acc[2][4];
    {
        f32x4 z = {0.f, 0.f, 0.f, 0.f};
        #pragma unroll
        for (int mi = 0; mi < 2; ++mi)
            #pragma unroll
            for (int ni = 0; ni < 4; ++ni) acc[mi][ni] = z;
    }
    gemm_main<2>(X, BT, m0, n0, lds, acc);

    const int tid = threadIdx.x, w = tid >> 6, lane = tid & 63;
    const int lr = lane & 15, lg = lane >> 4;
    const int wm = (w >> 1) * 32, wn = (w & 1) * 64;
    #pragma unroll
    for (int mi = 0; mi < 2; ++mi)
        #pragma unroll
        for (int ni = 0; ni < 4; ++ni) {
            int n = n0 + wn + ni * 16 + lr;
            float bv = bout[n];
            #pragma unroll
            for (int r = 0; r < 4; ++r) {
                int rg = m0 + wm + mi * 16 + lg * 4 + r;
                out0[(size_t)rg * 640 + n] = acc[mi][ni][r] + bv;
            }
        }
}

extern "C" void kernel_launch(void* const* d_in, const int* in_sizes, int n_in,
                              void* d_out, int out_size, void* d_ws, size_t ws_size,
                              hipStream_t stream)
{
    (void)in_sizes; (void)n_in; (void)out_size; (void)ws_size;
    const float* Q    = (const float*)d_in[0];
    const float* WQ   = (const float*)d_in[1];
    const float* bQ   = (const float*)d_in[2];
    const float* WK   = (const float*)d_in[3];
    const float* bK   = (const float*)d_in[4];
    const float* WV   = (const float*)d_in[5];
    const float* bV   = (const float*)d_in[6];
    const float* Wpos = (const float*)d_in[7];
    const float* Wagg = (const float*)d_in[8];
    const float* bagg = (const float*)d_in[9];
    const float* WO   = (const float*)d_in[10];
    const float* bout = (const float*)d_in[11];

    float* out0  = (float*)d_out;
    float* gattn = out0 + (size_t)MROWS * DIMN;   // attn output region (268 MB)

    char* ws = (char*)d_ws;
    bf16* Qbf    = (bf16*)(ws);                 ws += (size_t)MROWS * DIMN * 2;      // 5.24 MB
    bf16* BTqkv  = (bf16*)(ws);                 ws += (size_t)1920 * 640 * 2;        // 2.46 MB
    bf16* BTout  = (bf16*)(ws);                 ws += (size_t)640 * 640 * 2;         // 0.82 MB
    bf16* qsbuf  = (bf16*)(ws);                 ws += (size_t)4 * 8 * 2048 * 64 * 2; // 8 MB (q+k)
    bf16* vsT    = (bf16*)(ws);                 ws += (size_t)16 * 64 * 2048 * 2;    // 4 MB
    float* aggbuf= (float*)(ws);                ws += (size_t)3 * MROWS * AGGD * 4;  // 6 MB
    bf16* xcat   = (bf16*)(ws);                 ws += (size_t)MROWS * DIMN * 2;      // 5.24 MB

    k_split_q<<<dim3(2560), dim3(256), 0, stream>>>(Q, Qbf);
    k_prep_w<<<dim3(100, 4), dim3(256), 0, stream>>>(WQ, WK, WV, WO, BTqkv, BTout);
    k_gemm_qkv<<<dim3(32, 15), dim3(256), 0, stream>>>(Qbf, BTqkv,
                                                       bQ, bK, bV, Wpos, qsbuf, vsT, aggbuf);
    k_agg<<<dim3(128), dim3(256), 0, stream>>>(aggbuf, Wagg, bagg, xcat);
    k_attn<<<dim3(32, 16), dim3(256), 0, stream>>>(qsbuf, vsT, gattn, xcat);
    k_gemm_out<<<dim3(64, 5), dim3(256), 0, stream>>>(xcat, BTout, bout, out0);
}

// Round 14
// 159.357 us; speedup vs baseline: 1.1402x; 1.0129x over previous
//
#include <hip/hip_runtime.h>
#include <cstdint>
#include <cstddef>

// Problem constants
#define BSZ   2
#define QL    2048
#define DIMN  640
#define NH    8
#define CMAIN 512
#define AGGD  128
#define MROWS 4096                 // BSZ*QL
#define SCALE_QK 0.11180339887498948f   // (DIM/NHEADS)^-0.5 = 80^-0.5
#define C2EXP (SCALE_QK * 1.4426950408889634f)   // scale * log2(e)

typedef __bf16 bf16;
typedef __bf16 bf16x8 __attribute__((ext_vector_type(8)));
typedef __bf16 bf16x4v __attribute__((ext_vector_type(4)));
typedef float  f32x4  __attribute__((ext_vector_type(4)));

typedef __attribute__((address_space(1))) const uint32_t GU32;
typedef __attribute__((address_space(3))) uint32_t LU32;
#define GLL(g, l) __builtin_amdgcn_global_load_lds((GU32*)(g), (LU32*)(l), 16, 0, 0)

// hardware transcendentals (base-2): v_exp_f32 / v_log_f32
#define EXP2F(x) __builtin_amdgcn_exp2f(x)
#define LOG2F(x) __builtin_amdgcn_logf(x)

static __device__ __forceinline__ f32x4 mfma16(bf16x8 a, bf16x8 b, f32x4 c) {
    return __builtin_amdgcn_mfma_f32_16x16x32_bf16(a, b, c, 0, 0, 0);
}

static __device__ __forceinline__ void waitbar() {
    asm volatile("s_waitcnt vmcnt(0)" ::: "memory");
    __builtin_amdgcn_s_barrier();
    asm volatile("" ::: "memory");
}

// LDS tiles: rows of ROWB bytes, XOR-swizzled byte ^= (row&7)<<4.
// global_load_lds writes LDS linearly, so the swizzle is applied by
// inverse-swizzling the per-lane GLOBAL source address (both-sides rule #21).
template<int ROWB>
static __device__ __forceinline__ bf16x8 ldsfragR(const bf16* base, int row, int kbyte) {
    return *(const bf16x8*)((const char*)base + row * ROWB + (kbyte ^ ((row & 7) << 4)));
}

// stage NCH 16B-chunks into LDS rows of ROWB bytes from global rows of strideB.
template<int NCH, int ROWB>
static __device__ __forceinline__ void stage_rowsR(bf16* ldsbuf, const char* gbase,
                                                   int strideB, int tid) {
    const int w = tid >> 6, lane = tid & 63;
    #pragma unroll
    for (int i = 0; i < NCH / 256; ++i) {
        int c = i * 256 + w * 64 + lane;
        int r = c / (ROWB / 16);
        int kb = ((c % (ROWB / 16)) * 16) ^ ((r & 7) << 4);   // inverse-swizzled
        GLL(gbase + (size_t)r * strideB + kb,
            (char*)ldsbuf + (size_t)(i * 256 + w * 64) * 16);
    }
}

// Plain-bf16 GEMM mainloop (fp32 MFMA accumulate). C = A*B; A [M][640] bf16,
// B^T [n][k=640] bf16. Block tile (MI*32)x128, 4 waves 2x2. Double-buffered,
// 1 barrier per 64-K chunk, 10 chunks.
template<int MI>
static __device__ __forceinline__ void gemm_main(
    const bf16* __restrict__ A, const bf16* __restrict__ BT,
    int m0, int n0, bf16* lds, f32x4 acc[MI][4])
{
    const int tid = threadIdx.x;
    const int w = tid >> 6, lane = tid & 63;
    const int lr = lane & 15, lg = lane >> 4;
    const int wm = (w >> 1) * (MI * 16), wn = (w & 1) * 64;
    constexpr int ASZ = MI * 2048;          // A-tile bf16 elems (MI*32 rows x 64)
    constexpr int BUF = ASZ + 8192;

    stage_rowsR<MI * 256, 128>(lds,   (const char*)(A + (size_t)m0 * 640), 1280, tid);
    stage_rowsR<1024, 128>(lds + ASZ, (const char*)(BT + (size_t)n0 * 640), 1280, tid);
    int cur = 0;
    #pragma unroll 1
    for (int ch = 0; ch < 10; ++ch) {
        waitbar();                                   // drain cur's loads; all waves synced
        if (ch < 9) {
            int kk = (ch + 1) * 64;
            bf16* nb = lds + (cur ^ 1) * BUF;
            stage_rowsR<MI * 256, 128>(nb,   (const char*)(A + (size_t)m0 * 640 + kk), 1280, tid);
            stage_rowsR<1024, 128>(nb + ASZ, (const char*)(BT + (size_t)n0 * 640 + kk), 1280, tid);
        }
        const bf16* cA = lds + cur * BUF;
        const bf16* cB = cA + ASZ;
        #pragma unroll
        for (int ks = 0; ks < 2; ++ks) {
            bf16x8 a[MI], b[4];
            #pragma unroll
            for (int i = 0; i < MI; ++i) a[i] = ldsfragR<128>(cA, wm + i * 16 + lr, ks * 64 + lg * 16);
            #pragma unroll
            for (int i = 0; i < 4; ++i)  b[i] = ldsfragR<128>(cB, wn + i * 16 + lr, ks * 64 + lg * 16);
            #pragma unroll
            for (int mi = 0; mi < MI; ++mi)
                #pragma unroll
                for (int ni = 0; ni < 4; ++ni)
                    acc[mi][ni] = mfma16(a[mi], b[ni], acc[mi][ni]);
        }
        cur ^= 1;
    }
}

// ---- prep: Q (4096x640 f32) -> bf16 ----
__global__ void __launch_bounds__(256) k_split_q(const float* __restrict__ Q,
                                                 bf16* __restrict__ Qbf) {
    int i = blockIdx.x * 256 + threadIdx.x;
    float4 v = ((const float4*)Q)[i];
    bf16x4v hv;
    hv[0] = (bf16)v.x; hv[1] = (bf16)v.y; hv[2] = (bf16)v.z; hv[3] = (bf16)v.w;
    *(bf16x4v*)(Qbf + (size_t)i * 4) = hv;
}

// ---- prep: coalesced LDS-transpose of W_Q/W_K/W_V/W_out into B^T bf16.
__global__ void __launch_bounds__(256) k_prep_w(
    const float* __restrict__ WQ, const float* __restrict__ WK,
    const float* __restrict__ WV, const float* __restrict__ WO,
    bf16* __restrict__ BTqkv, bf16* __restrict__ BTout)
{
    __shared__ float tl[64][65];     // tl[n_loc][k_loc]
    const int ty = blockIdx.x / 10, tx = blockIdx.x % 10;
    const int wsel = blockIdx.y;
    const float* W = (wsel == 0) ? WQ : (wsel == 1) ? WK : (wsel == 2) ? WV : WO;
    const int tid = threadIdx.x;
    const int rr = tid >> 4;             // k row group 0..15
    const int cc = (tid & 15) * 4;       // n col 0..60
    #pragma unroll
    for (int i = 0; i < 4; ++i) {
        int k = tx * 64 + rr + i * 16;
        float4 v = *(const float4*)(W + (size_t)k * 640 + ty * 64 + cc);
        tl[cc + 0][rr + i * 16] = v.x;
        tl[cc + 1][rr + i * 16] = v.y;
        tl[cc + 2][rr + i * 16] = v.z;
        tl[cc + 3][rr + i * 16] = v.w;
    }
    __syncthreads();
    bf16* dst; int nbase;
    if (wsel < 3) { dst = BTqkv; nbase = wsel * 640 + ty * 64; }
    else          { dst = BTout; nbase = ty * 64; }
    const int nl0 = tid >> 4;
    const int kl = (tid & 15) * 4;
    #pragma unroll
    for (int i = 0; i < 4; ++i) {
        int nl = nl0 + i * 16;
        bf16x4v hv;
        #pragma unroll
        for (int j = 0; j < 4; ++j) hv[j] = (bf16)tl[nl][kl + j];
        *(bf16x4v*)(dst + (size_t)(nbase + nl) * 640 + tx * 64 + kl) = hv;
    }
}

// ---- QKV GEMM: C[4096][1920] ; epilogue adds bias (+W_pos) and routes outputs
__global__ void __launch_bounds__(256) k_gemm_qkv(
    const bf16* __restrict__ Qbf, const bf16* __restrict__ BT,
    const float* __restrict__ bQ, const float* __restrict__ bK, const float* __restrict__ bV,
    const float* __restrict__ Wpos,
    bf16* __restrict__ qsbuf, bf16* __restrict__ vsT, float* __restrict__ aggbuf)
{
    __shared__ __align__(16) bf16 lds[2 * (8192 + 8192)];   // 64 KB
    const int m0 = blockIdx.x * 128, n0 = blockIdx.y * 128;
    f32x4 acc[4][4];
    {
        f32x4 z = {0.f, 0.f, 0.f, 0.f};
        #pragma unroll
        for (int mi = 0; mi < 4; ++mi)
            #pragma unroll
            for (int ni = 0; ni < 4; ++ni) acc[mi][ni] = z;
    }
    gemm_main<4>(Qbf, BT, m0, n0, lds, acc);

    const int tid = threadIdx.x, w = tid >> 6, lane = tid & 63;
    const int lr = lane & 15, lg = lane >> 4;
    const int wm = (w >> 1) * 64, wn = (w & 1) * 64;
    const int p = n0 / 640;                       // block-uniform (640 % 128 == 0)
    const float* bias = (p == 0) ? bQ : (p == 1) ? bK : bV;

    #pragma unroll
    for (int mi = 0; mi < 4; ++mi)
        #pragma unroll
        for (int ni = 0; ni < 4; ++ni) {
            int n = n0 + wn + ni * 16 + lr;
            int c = n - p * 640;
            int rbase = m0 + wm + mi * 16 + lg * 4;
            float bval = bias[c];
            if (c < 512) {
                int hh = c >> 6, d = c & 63;
                #pragma unroll
                for (int r = 0; r < 4; ++r) {
                    int rg = rbase + r;
                    int bb = rg >> 11, l = rg & 2047;
                    float v = acc[mi][ni][r] + bval + Wpos[(size_t)l * 512 + c];
                    if (p < 2)
                        qsbuf[(((size_t)(p * 2 + bb) * 8 + hh) * 2048 + l) * 64 + d] = (bf16)v;
                    else
                        vsT[(((size_t)(bb * 8 + hh)) * 64 + d) * 2048 + l] = (bf16)v;
                }
            } else {
                int j = c - 512;
                #pragma unroll
                for (int r = 0; r < 4; ++r) {
                    int rg = rbase + r;
                    aggbuf[((size_t)p * MROWS + rg) * AGGD + j] = acc[mi][ni][r] + bval;
                }
            }
        }
}

// ---- agg: x = mean3(aggbuf) ; gelu_tanh(x @ W_agg + b_agg) -> xcat cols 512..639
__global__ void __launch_bounds__(256) k_agg(const float* __restrict__ aggbuf,
                                             const float* __restrict__ Wagg, const float* __restrict__ bagg,
                                             bf16* __restrict__ xcat)
{
    __shared__ float wl[128 * 128];
    __shared__ float xl[32 * 128];
    const int tid = threadIdx.x;
    const int r0 = blockIdx.x * 32;
    for (int i = tid; i < 128 * 128; i += 256) wl[i] = Wagg[i];
    for (int i = tid; i < 32 * 128; i += 256) {
        int row = i >> 7, j = i & 127;
        size_t rg = r0 + row;
        float s = aggbuf[rg * AGGD + j]
                + aggbuf[((size_t)MROWS + rg) * AGGD + j]
                + aggbuf[((size_t)2 * MROWS + rg) * AGGD + j];
        xl[i] = s * (1.0f / 3.0f);
    }
    __syncthreads();
    const int row = tid >> 3;
    const int jo0 = (tid & 7) * 16;
    float acc[16];
    #pragma unroll
    for (int jj = 0; jj < 16; ++jj) acc[jj] = 0.f;
    for (int j = 0; j < 128; ++j) {
        float xv = xl[row * 128 + j];
        const float* wr = &wl[j * 128 + jo0];
        #pragma unroll
        for (int jj = 0; jj < 16; ++jj) acc[jj] = fmaf(xv, wr[jj], acc[jj]);
    }
    size_t rg = r0 + row;
    #pragma unroll
    for (int jj = 0; jj < 16; ++jj) {
        float t = acc[jj] + bagg[jo0 + jj];
        float g = 0.5f * t * (1.0f + tanhf(0.7978845608028654f * (t + 0.044715f * t * t * t)));
        xcat[rg * 640 + 512 + jo0 + jj] = (bf16)g;
    }
}

// ---- attention, NO-MAX softmax, SWAPPED QK^T (T12): s = mfma(K_frag, Q_frag)
// gives lane-local P rows: lane holds P[q=lr][k=ni*16+lg*4+r].
// pass1: BK=128, per-lane exp2 sums, reduce via shfl_xor(16/32).
// pass2: BK=128, p = exp2(fma(s,C2,l2i)) (normalization folded into exponent),
// float4 attn stores, packed b64 p_lds writes, counted vmcnt(8).
__global__ void __launch_bounds__(256) k_attn(const bf16* __restrict__ qsbuf, const bf16* __restrict__ vsT,
                                              float* __restrict__ gattn,
                                              bf16* __restrict__ xcat)
{
    __shared__ __align__(16) bf16 smem[2][16384];       // 64 KB: K[128][128B] + V[64][256B]
    __shared__ __align__(16) bf16 p_lds[4][16 * 128];   // 16 KB, per-wave [16 q][256B]

    const int bh = blockIdx.y;
    const int b = bh >> 3, h = bh & 7;
    const int q0 = blockIdx.x * 64;
    const int tid = threadIdx.x, w = tid >> 6, lane = tid & 63;
    const int lr = lane & 15, lg = lane >> 4;

    const bf16* qbase = qsbuf + (size_t)(b * 8 + h) * (2048 * 64);          // q
    const bf16* kbase = qsbuf + (size_t)((2 + b) * 8 + h) * (2048 * 64);    // k
    const bf16* vtb   = vsT + (size_t)(b * 8 + h) * (64 * 2048);

    bf16x8 aq[2];
    {
        const bf16* qp = qbase + (size_t)(q0 + w * 16 + lr) * 64 + lg * 8;
        aq[0] = *(const bf16x8*)(qp);
        aq[1] = *(const bf16x8*)(qp + 32);
    }

    // ---- pass 1: denominator sums, BK=128
    float lsum = 0.f;
    stage_rowsR<1024, 128>(smem[0], (const char*)kbase, 128, tid);
    int cur = 0;
    #pragma unroll 1
    for (int kt = 0; kt < 16; ++kt) {
        waitbar();
        if (kt < 15)
            stage_rowsR<1024, 128>(smem[cur ^ 1], (const char*)kbase + (size_t)(kt + 1) * 16384, 128, tid);
        __builtin_amdgcn_sched_barrier(0);
        const bf16* kb = smem[cur];
        f32x4 s[8];
        {
            f32x4 z = {0.f, 0.f, 0.f, 0.f};
            #pragma unroll
            for (int ni = 0; ni < 8; ++ni) s[ni] = z;
        }
        #pragma unroll
        for (int ks = 0; ks < 2; ++ks)
            #pragma unroll
            for (int ni = 0; ni < 8; ++ni)
                s[ni] = mfma16(ldsfragR<128>(kb, ni * 16 + lr, ks * 64 + lg * 16), aq[ks], s[ni]);
        #pragma unroll
        for (int ni = 0; ni < 8; ++ni)
            #pragma unroll
            for (int r = 0; r < 4; ++r)
                lsum += EXP2F(s[ni][r] * C2EXP);
        cur ^= 1;
    }
    lsum += __shfl_xor(lsum, 16);
    lsum += __shfl_xor(lsum, 32);
    const float l2i = -LOG2F(lsum);

    f32x4 o[4];
    {
        f32x4 z = {0.f, 0.f, 0.f, 0.f};
        #pragma unroll
        for (int ni = 0; ni < 4; ++ni) o[ni] = z;
    }
    float* attnrow = gattn + (size_t)bh * 2048 * 2048 + (size_t)(q0 + w * 16 + lr) * 2048;

    // ---- pass 2: BK=128; K in smem[cur][0..8191], V^T in smem[cur][8192..]
    stage_rowsR<1024, 128>(smem[0],        (const char*)kbase, 128, tid);
    stage_rowsR<1024, 256>(smem[0] + 8192, (const char*)vtb, 4096, tid);
    cur = 0;
    #pragma unroll 1
    for (int kt = 0; kt < 16; ++kt) {
        // drain the 8 staging loads; stores (8/lane, newer in FIFO) may remain
        if (kt == 0) asm volatile("s_waitcnt vmcnt(0)" ::: "memory");
        else         asm volatile("s_waitcnt vmcnt(8)" ::: "memory");
        __builtin_amdgcn_s_barrier();
        asm volatile("" ::: "memory");
        if (kt < 15) {
            stage_rowsR<1024, 128>(smem[cur ^ 1],        (const char*)kbase + (size_t)(kt + 1) * 16384, 128, tid);
            stage_rowsR<1024, 256>(smem[cur ^ 1] + 8192, (const char*)vtb + (size_t)(kt + 1) * 256, 4096, tid);
        }
        __builtin_amdgcn_sched_barrier(0);   // keep staging issue ahead of compute/stores
        const bf16* kb = smem[cur];
        const bf16* vb = smem[cur] + 8192;
        f32x4 s[8];
        {
            f32x4 z = {0.f, 0.f, 0.f, 0.f};
            #pragma unroll
            for (int ni = 0; ni < 8; ++ni) s[ni] = z;
        }
        #pragma unroll
        for (int ks = 0; ks < 2; ++ks)
            #pragma unroll
            for (int ni = 0; ni < 8; ++ni)
                s[ni] = mfma16(ldsfragR<128>(kb, ni * 16 + lr, ks * 64 + lg * 16), aq[ks], s[ni]);
        bf16* pl = &p_lds[w][0];
        float* arow = attnrow + kt * 128;
        #pragma unroll
        for (int ni = 0; ni < 8; ++ni) {
            f32x4 p;
            #pragma unroll
            for (int r = 0; r < 4; ++r) p[r] = EXP2F(fmaf(s[ni][r], C2EXP, l2i));
            *(f32x4*)(arow + ni * 16 + lg * 4) = p;          // dwordx4 attn store
            bf16x4v pb;
            #pragma unroll
            for (int r = 0; r < 4; ++r) pb[r] = (bf16)p[r];
            *(bf16x4v*)((char*)pl + lr * 256 + ((ni * 32 + lg * 8) ^ ((lr & 7) << 4))) = pb;
        }
        #pragma unroll
        for (int ks = 0; ks < 4; ++ks) {
            bf16x8 pa = ldsfragR<256>(pl, lr, ks * 64 + lg * 16);
            #pragma unroll
            for (int ni = 0; ni < 4; ++ni)
                o[ni] = mfma16(pa, ldsfragR<256>(vb, ni * 16 + lr, ks * 64 + lg * 16), o[ni]);
        }
        cur ^= 1;
    }

    #pragma unroll
    for (int ni = 0; ni < 4; ++ni) {
        #pragma unroll
        for (int r = 0; r < 4; ++r) {
            int qr = q0 + w * 16 + lg * 4 + r;
            size_t rg = (size_t)b * 2048 + qr;
            int c = h * 64 + ni * 16 + lr;
            xcat[rg * 640 + c] = (bf16)o[ni][r];
        }
    }
}

// ---- out GEMM (BM=64 for occupancy: 320 blocks): d_out = xcat @ W_out + b_out
__global__ void __launch_bounds__(256) k_gemm_out(
    const bf16* __restrict__ X, const bf16* __restrict__ BT,
    const float* __restrict__ bout, float* __restrict__ out0)
{
    __shared__ __align__(16) bf16 lds[2 * (4096 + 8192)];   // 48 KB
    const int m0 = blockIdx.x * 64, n0 = blockIdx.y * 128;
    f32x4 acc[2][4];
    {
        f32x4 z = {0.f, 0.f, 0.f, 0.f};
        #pragma unroll
        for (int mi = 0; mi < 2; ++mi)
            #pragma unroll
            for (int ni = 0; ni < 4; ++ni) acc[mi][ni] = z;
    }
    gemm_main<2>(X, BT, m0, n0, lds, acc);

    const int tid = threadIdx.x, w = tid >> 6, lane = tid & 63;
    const int lr = lane & 15, lg = lane >> 4;
    const int wm = (w >> 1) * 32, wn = (w & 1) * 64;
    #pragma unroll
    for (int mi = 0; mi < 2; ++mi)
        #pragma unroll
        for (int ni = 0; ni < 4; ++ni) {
            int n = n0 + wn + ni * 16 + lr;
            float bv = bout[n];
            #pragma unroll
            for (int r = 0; r < 4; ++r) {
                int rg = m0 + wm + mi * 16 + lg * 4 + r;
                out0[(size_t)rg * 640 + n] = acc[mi][ni][r] + bv;
            }
        }
}

extern "C" void kernel_launch(void* const* d_in, const int* in_sizes, int n_in,
                              void* d_out, int out_size, void* d_ws, size_t ws_size,
                              hipStream_t stream)
{
    (void)in_sizes; (void)n_in; (void)out_size; (void)ws_size;
    const float* Q    = (const float*)d_in[0];
    const float* WQ   = (const float*)d_in[1];
    const float* bQ   = (const float*)d_in[2];
    const float* WK   = (const float*)d_in[3];
    const float* bK   = (const float*)d_in[4];
    const float* WV   = (const float*)d_in[5];
    const float* bV   = (const float*)d_in[6];
    const float* Wpos = (const float*)d_in[7];
    const float* Wagg = (const float*)d_in[8];
    const float* bagg = (const float*)d_in[9];
    const float* WO   = (const float*)d_in[10];
    const float* bout = (const float*)d_in[11];

    float* out0  = (float*)d_out;
    float* gattn = out0 + (size_t)MROWS * DIMN;   // attn output region (268 MB)

    char* ws = (char*)d_ws;
    bf16* Qbf    = (bf16*)(ws);                 ws += (size_t)MROWS * DIMN * 2;      // 5.24 MB
    bf16* BTqkv  = (bf16*)(ws);                 ws += (size_t)1920 * 640 * 2;        // 2.46 MB
    bf16* BTout  = (bf16*)(ws);                 ws += (size_t)640 * 640 * 2;         // 0.82 MB
    bf16* qsbuf  = (bf16*)(ws);                 ws += (size_t)4 * 8 * 2048 * 64 * 2; // 8 MB (q+k)
    bf16* vsT    = (bf16*)(ws);                 ws += (size_t)16 * 64 * 2048 * 2;    // 4 MB
    float* aggbuf= (float*)(ws);                ws += (size_t)3 * MROWS * AGGD * 4;  // 6 MB
    bf16* xcat   = (bf16*)(ws);                 ws += (size_t)MROWS * DIMN * 2;      // 5.24 MB

    k_split_q<<<dim3(2560), dim3(256), 0, stream>>>(Q, Qbf);
    k_prep_w<<<dim3(100, 4), dim3(256), 0, stream>>>(WQ, WK, WV, WO, BTqkv, BTout);
    k_gemm_qkv<<<dim3(32, 15), dim3(256), 0, stream>>>(Qbf, BTqkv,
                                                       bQ, bK, bV, Wpos, qsbuf, vsT, aggbuf);
    k_agg<<<dim3(128), dim3(256), 0, stream>>>(aggbuf, Wagg, bagg, xcat);
    k_attn<<<dim3(32, 16), dim3(256), 0, stream>>>(qsbuf, vsT, gattn, xcat);
    k_gemm_out<<<dim3(64, 5), dim3(256), 0, stream>>>(xcat, BTout, bout, out0);
}